// Round 1
// baseline (730.496 us; speedup 1.0000x reference)
//
#include <hip/hip_runtime.h>
#include <cstdint>
#include <cstddef>

// ---------------------------------------------------------------------------
// GCN 3-layer forward on MI355X.
// Pipeline per call: detect idx dtype -> degree -> dis=rsqrt(deg) ->
// CSR build (hist, 2-level scan, fill) -> 3x [GEMM(+dis scale) -> CSR agg
// (+dis scale +bias +gelu)].
// ---------------------------------------------------------------------------

__device__ __forceinline__ int eload(const int* ei, int elem, int is64) {
  // edge_index element `elem` (flat, row-major (2,E)); if stored as int64
  // little-endian, value lives in word 2*elem.
  return is64 ? ei[2 * elem] : ei[elem];
}

// Detect int64 vs int32 storage: for int64, high words (odd word positions)
// of the first 1024 elements are all zero (values in [0, N) < 2^31).
__global__ void k_detect(const int* __restrict__ ei, int* __restrict__ flag) {
  __shared__ int sh[256];
  int tid = threadIdx.x;
  int o = 0;
  for (int i = tid; i < 1024; i += 256) o |= ei[2 * i + 1];
  sh[tid] = o;
  __syncthreads();
  for (int s = 128; s > 0; s >>= 1) {
    if (tid < s) sh[tid] |= sh[tid + s];
    __syncthreads();
  }
  if (tid == 0) *flag = (sh[0] == 0) ? 1 : 0;
}

__global__ __launch_bounds__(256) void k_zero(int* __restrict__ p, int n) {
  int i = blockIdx.x * 256 + threadIdx.x;
  if (i < n) p[i] = 0;
}

__global__ __launch_bounds__(256) void k_count(const int* __restrict__ ei,
                                               int* __restrict__ cnt, int E,
                                               const int* __restrict__ flag) {
  int e = blockIdx.x * 256 + threadIdx.x;
  if (e >= E) return;
  int is64 = *flag;
  int d = eload(ei, E + e, is64);
  atomicAdd(&cnt[d], 1);
}

__global__ __launch_bounds__(256) void k_dis(const int* __restrict__ cnt,
                                             float* __restrict__ dis, int N) {
  int i = blockIdx.x * 256 + threadIdx.x;
  if (i < N) dis[i] = rsqrtf((float)(cnt[i] + 1));  // +1 self loop
}

// exclusive scan, 1024 elements per block (256 thr x 4)
__global__ __launch_bounds__(256) void k_scan1(const int* __restrict__ cnt,
                                               int* __restrict__ off,
                                               int* __restrict__ bsum, int N) {
  __shared__ int sh[256];
  int tid = threadIdx.x;
  int base = blockIdx.x * 1024 + tid * 4;
  int v0 = (base + 0 < N) ? cnt[base + 0] : 0;
  int v1 = (base + 1 < N) ? cnt[base + 1] : 0;
  int v2 = (base + 2 < N) ? cnt[base + 2] : 0;
  int v3 = (base + 3 < N) ? cnt[base + 3] : 0;
  int tsum = v0 + v1 + v2 + v3;
  sh[tid] = tsum;
  __syncthreads();
  for (int o = 1; o < 256; o <<= 1) {
    int x = (tid >= o) ? sh[tid - o] : 0;
    __syncthreads();
    sh[tid] += x;
    __syncthreads();
  }
  int excl = sh[tid] - tsum;
  if (base + 0 < N) off[base + 0] = excl;
  if (base + 1 < N) off[base + 1] = excl + v0;
  if (base + 2 < N) off[base + 2] = excl + v0 + v1;
  if (base + 3 < N) off[base + 3] = excl + v0 + v1 + v2;
  if (tid == 255) bsum[blockIdx.x] = sh[255];
}

__global__ __launch_bounds__(256) void k_scan2(int* __restrict__ bsum, int NB) {
  __shared__ int sh[256];
  int tid = threadIdx.x;
  int v = (tid < NB) ? bsum[tid] : 0;
  sh[tid] = v;
  __syncthreads();
  for (int o = 1; o < 256; o <<= 1) {
    int x = (tid >= o) ? sh[tid - o] : 0;
    __syncthreads();
    sh[tid] += x;
    __syncthreads();
  }
  if (tid < NB) bsum[tid] = sh[tid] - v;  // exclusive
}

__global__ __launch_bounds__(256) void k_scan3(int* __restrict__ off,
                                               const int* __restrict__ bsum,
                                               int* __restrict__ cursor, int N,
                                               int E) {
  int i = blockIdx.x * 256 + threadIdx.x;
  if (i == 0) off[N] = E;
  if (i < N) {
    int o = off[i] + bsum[i >> 10];
    off[i] = o;
    cursor[i] = o;
  }
}

__global__ __launch_bounds__(256) void k_fill(const int* __restrict__ ei,
                                              int* __restrict__ cursor,
                                              int* __restrict__ csr, int E,
                                              const int* __restrict__ flag) {
  int e = blockIdx.x * 256 + threadIdx.x;
  if (e >= E) return;
  int is64 = *flag;
  int s = eload(ei, e, is64);
  int d = eload(ei, E + e, is64);
  int pos = atomicAdd(&cursor[d], 1);
  csr[pos] = s;
}

// G = (X @ W) * dis[row]; W staged in LDS; 16 rows per block of 256.
template <int K, int M, int ROWS>
__global__ __launch_bounds__(256) void k_gemm_scale(
    const float* __restrict__ X, const float* __restrict__ W,
    const float* __restrict__ dis, float* __restrict__ G, int N) {
  constexpr int GROUPS = 256 / M;     // 2 (M=128) or 4 (M=64)
  constexpr int RPT = ROWS / GROUPS;  // rows per thread
  __shared__ float Wl[K * M];
  __shared__ float Xl[ROWS * K];
  int tid = threadIdx.x;
  const float4* W4 = (const float4*)W;
  float4* Wl4 = (float4*)Wl;
  for (int i = tid; i < K * M / 4; i += 256) Wl4[i] = W4[i];
  int row0 = blockIdx.x * ROWS;
  int valid_rows = min(ROWS, N - row0);
  const float4* X4 = (const float4*)(X + (size_t)row0 * K);
  float4* Xl4 = (float4*)Xl;
  int xcnt = valid_rows * K / 4;
  for (int i = tid; i < xcnt; i += 256) Xl4[i] = X4[i];
  __syncthreads();
  int c = tid % M;
  int rg = tid / M;
  float acc[RPT];
#pragma unroll
  for (int r = 0; r < RPT; r++) acc[r] = 0.f;
#pragma unroll 8
  for (int k = 0; k < K; k++) {
    float wv = Wl[k * M + c];
#pragma unroll
    for (int r = 0; r < RPT; r++) acc[r] += Xl[(rg * RPT + r) * K + k] * wv;
  }
#pragma unroll
  for (int r = 0; r < RPT; r++) {
    int row = row0 + rg * RPT + r;
    if (row < N) G[(size_t)row * M + c] = acc[r] * dis[row];
  }
}

__device__ __forceinline__ float gelu_exact(float v) {
  return 0.5f * v * (1.0f + erff(v * 0.70710678118654752440f));
}

// out[d] = dis[d]*(sum_{s in CSR[d]} g[s] + g[d]) + b ; optional GELU.
// One wave (64 lanes) per node; VPL floats per lane.
template <int D, bool APPLY_GELU>
__global__ __launch_bounds__(256) void k_agg(
    const float* __restrict__ g, const int* __restrict__ off,
    const int* __restrict__ csr, const float* __restrict__ dis,
    const float* __restrict__ bias, float* __restrict__ out, int N) {
  constexpr int VPL = D / 64;  // 2 for D=128, 1 for D=64
  int wid = (blockIdx.x * 256 + threadIdx.x) >> 6;
  int lane = threadIdx.x & 63;
  if (wid >= N) return;
  int d = wid;
  float acc0, acc1 = 0.f;
  if constexpr (VPL == 2) {
    float2 s = *(const float2*)(g + (size_t)d * D + lane * 2);
    acc0 = s.x;
    acc1 = s.y;
  } else {
    acc0 = g[(size_t)d * D + lane];
  }
  int beg = off[d], end = off[d + 1];
  int j = beg;
  for (; j + 4 <= end; j += 4) {
    int s0 = csr[j], s1 = csr[j + 1], s2 = csr[j + 2], s3 = csr[j + 3];
    if constexpr (VPL == 2) {
      float2 a = *(const float2*)(g + (size_t)s0 * D + lane * 2);
      float2 b = *(const float2*)(g + (size_t)s1 * D + lane * 2);
      float2 c = *(const float2*)(g + (size_t)s2 * D + lane * 2);
      float2 e = *(const float2*)(g + (size_t)s3 * D + lane * 2);
      acc0 += a.x + b.x + c.x + e.x;
      acc1 += a.y + b.y + c.y + e.y;
    } else {
      acc0 += g[(size_t)s0 * D + lane] + g[(size_t)s1 * D + lane] +
              g[(size_t)s2 * D + lane] + g[(size_t)s3 * D + lane];
    }
  }
  for (; j < end; j++) {
    int s0 = csr[j];
    if constexpr (VPL == 2) {
      float2 a = *(const float2*)(g + (size_t)s0 * D + lane * 2);
      acc0 += a.x;
      acc1 += a.y;
    } else {
      acc0 += g[(size_t)s0 * D + lane];
    }
  }
  float dd = dis[d];
  if constexpr (VPL == 2) {
    int c0 = lane * 2;
    float v0 = acc0 * dd + bias[c0];
    float v1 = acc1 * dd + bias[c0 + 1];
    if constexpr (APPLY_GELU) {
      v0 = gelu_exact(v0);
      v1 = gelu_exact(v1);
    }
    float2 o = {v0, v1};
    *(float2*)(out + (size_t)d * D + c0) = o;
  } else {
    float v0 = acc0 * dd + bias[lane];
    if constexpr (APPLY_GELU) v0 = gelu_exact(v0);
    out[(size_t)d * D + lane] = v0;
  }
}

extern "C" void kernel_launch(void* const* d_in, const int* in_sizes, int n_in,
                              void* d_out, int out_size, void* d_ws,
                              size_t ws_size, hipStream_t stream) {
  const float* x = (const float*)d_in[0];
  const int* ei = (const int*)d_in[1];
  const float* W1 = (const float*)d_in[2];
  const float* b1 = (const float*)d_in[3];
  const float* W2 = (const float*)d_in[4];
  const float* b2 = (const float*)d_in[5];
  const float* W3 = (const float*)d_in[6];
  const float* b3 = (const float*)d_in[7];
  float* out = (float*)d_out;

  const int N = in_sizes[0] / 64;
  const int E = in_sizes[1] / 2;

  // workspace carve (aligned 256B). Total ~110 MB.
  char* p = (char*)d_ws;
  auto alloc = [&](size_t bytes) {
    char* r = p;
    p += (bytes + 255) & ~(size_t)255;
    return r;
  };
  float* dis = (float*)alloc((size_t)N * 4);
  int* cnt = (int*)alloc((size_t)N * 4);
  int* off = (int*)alloc((size_t)(N + 1) * 4);
  int* cursor = (int*)alloc((size_t)N * 4);
  int* bsum = (int*)alloc(4096);
  int* flag = (int*)alloc(256);
  int* csr = (int*)alloc((size_t)E * 4);
  float* bufA = (float*)alloc((size_t)N * 128 * 4);
  float* bufB = (float*)alloc((size_t)N * 128 * 4);

  const int NB = (N + 1023) / 1024;

  k_detect<<<1, 256, 0, stream>>>(ei, flag);
  k_zero<<<(N + 255) / 256, 256, 0, stream>>>(cnt, N);
  k_count<<<(E + 255) / 256, 256, 0, stream>>>(ei, cnt, E, flag);
  k_dis<<<(N + 255) / 256, 256, 0, stream>>>(cnt, dis, N);
  k_scan1<<<NB, 256, 0, stream>>>(cnt, off, bsum, N);
  k_scan2<<<1, 256, 0, stream>>>(bsum, NB);
  k_scan3<<<(N + 255) / 256, 256, 0, stream>>>(off, bsum, cursor, N, E);
  k_fill<<<(E + 255) / 256, 256, 0, stream>>>(ei, cursor, csr, E, flag);

  const int gemm_blocks = (N + 15) / 16;
  const int agg_blocks = (N + 3) / 4;  // 4 waves / block, 1 wave / node

  // layer 1: x[N,64] @ W1[64,128] -> gelu(agg + b1)
  k_gemm_scale<64, 128, 16><<<gemm_blocks, 256, 0, stream>>>(x, W1, dis, bufA, N);
  k_agg<128, true><<<agg_blocks, 256, 0, stream>>>(bufA, off, csr, dis, b1, bufB, N);
  // layer 2: [N,128] @ W2[128,128]
  k_gemm_scale<128, 128, 16><<<gemm_blocks, 256, 0, stream>>>(bufB, W2, dis, bufA, N);
  k_agg<128, true><<<agg_blocks, 256, 0, stream>>>(bufA, off, csr, dis, b2, bufB, N);
  // layer 3: [N,128] @ W3[128,64] -> agg + b3 (no gelu)
  k_gemm_scale<128, 64, 16><<<gemm_blocks, 256, 0, stream>>>(bufB, W3, dis, bufA, N);
  k_agg<64, false><<<agg_blocks, 256, 0, stream>>>(bufA, off, csr, dis, b3, out, N);
}

// Round 2
// 636.755 us; speedup vs baseline: 1.1472x; 1.1472x over previous
//
#include <hip/hip_runtime.h>
#include <cstdint>
#include <cstddef>

// ---------------------------------------------------------------------------
// GCN 3-layer forward on MI355X.
// Pipeline per call: detect idx dtype -> degree -> dis=rsqrt(deg) ->
// CSR build (hist, 2-level scan, fill) -> 3x [GEMM(+dis scale) -> CSR agg
// (+dis scale +bias +gelu)].
// R1: register-tiled GEMM (BM=128, BK=16, 8x8 thread tile) replaces the
// LDS-broadcast GEMM that was issue-bound at 2 blocks/CU.
// ---------------------------------------------------------------------------

__device__ __forceinline__ int eload(const int* ei, int elem, int is64) {
  return is64 ? ei[2 * elem] : ei[elem];
}

// Detect int64 vs int32 storage: for int64, high words of the first 1024
// elements are all zero (values in [0, N) < 2^31).
__global__ void k_detect(const int* __restrict__ ei, int* __restrict__ flag) {
  __shared__ int sh[256];
  int tid = threadIdx.x;
  int o = 0;
  for (int i = tid; i < 1024; i += 256) o |= ei[2 * i + 1];
  sh[tid] = o;
  __syncthreads();
  for (int s = 128; s > 0; s >>= 1) {
    if (tid < s) sh[tid] |= sh[tid + s];
    __syncthreads();
  }
  if (tid == 0) *flag = (sh[0] == 0) ? 1 : 0;
}

__global__ __launch_bounds__(256) void k_zero(int* __restrict__ p, int n) {
  int i = blockIdx.x * 256 + threadIdx.x;
  if (i < n) p[i] = 0;
}

__global__ __launch_bounds__(256) void k_count(const int* __restrict__ ei,
                                               int* __restrict__ cnt, int E,
                                               const int* __restrict__ flag) {
  int e = blockIdx.x * 256 + threadIdx.x;
  if (e >= E) return;
  int is64 = *flag;
  int d = eload(ei, E + e, is64);
  atomicAdd(&cnt[d], 1);
}

__global__ __launch_bounds__(256) void k_dis(const int* __restrict__ cnt,
                                             float* __restrict__ dis, int N) {
  int i = blockIdx.x * 256 + threadIdx.x;
  if (i < N) dis[i] = rsqrtf((float)(cnt[i] + 1));  // +1 self loop
}

// exclusive scan, 1024 elements per block (256 thr x 4)
__global__ __launch_bounds__(256) void k_scan1(const int* __restrict__ cnt,
                                               int* __restrict__ off,
                                               int* __restrict__ bsum, int N) {
  __shared__ int sh[256];
  int tid = threadIdx.x;
  int base = blockIdx.x * 1024 + tid * 4;
  int v0 = (base + 0 < N) ? cnt[base + 0] : 0;
  int v1 = (base + 1 < N) ? cnt[base + 1] : 0;
  int v2 = (base + 2 < N) ? cnt[base + 2] : 0;
  int v3 = (base + 3 < N) ? cnt[base + 3] : 0;
  int tsum = v0 + v1 + v2 + v3;
  sh[tid] = tsum;
  __syncthreads();
  for (int o = 1; o < 256; o <<= 1) {
    int x = (tid >= o) ? sh[tid - o] : 0;
    __syncthreads();
    sh[tid] += x;
    __syncthreads();
  }
  int excl = sh[tid] - tsum;
  if (base + 0 < N) off[base + 0] = excl;
  if (base + 1 < N) off[base + 1] = excl + v0;
  if (base + 2 < N) off[base + 2] = excl + v0 + v1;
  if (base + 3 < N) off[base + 3] = excl + v0 + v1 + v2;
  if (tid == 255) bsum[blockIdx.x] = sh[255];
}

__global__ __launch_bounds__(256) void k_scan2(int* __restrict__ bsum, int NB) {
  __shared__ int sh[256];
  int tid = threadIdx.x;
  int v = (tid < NB) ? bsum[tid] : 0;
  sh[tid] = v;
  __syncthreads();
  for (int o = 1; o < 256; o <<= 1) {
    int x = (tid >= o) ? sh[tid - o] : 0;
    __syncthreads();
    sh[tid] += x;
    __syncthreads();
  }
  if (tid < NB) bsum[tid] = sh[tid] - v;  // exclusive
}

__global__ __launch_bounds__(256) void k_scan3(int* __restrict__ off,
                                               const int* __restrict__ bsum,
                                               int* __restrict__ cursor, int N,
                                               int E) {
  int i = blockIdx.x * 256 + threadIdx.x;
  if (i == 0) off[N] = E;
  if (i < N) {
    int o = off[i] + bsum[i >> 10];
    off[i] = o;
    cursor[i] = o;
  }
}

__global__ __launch_bounds__(256) void k_fill(const int* __restrict__ ei,
                                              int* __restrict__ cursor,
                                              int* __restrict__ csr, int E,
                                              const int* __restrict__ flag) {
  int e = blockIdx.x * 256 + threadIdx.x;
  if (e >= E) return;
  int is64 = *flag;
  int s = eload(ei, e, is64);
  int d = eload(ei, E + e, is64);
  int pos = atomicAdd(&cursor[d], 1);
  csr[pos] = s;
}

// ---------------------------------------------------------------------------
// Register-tiled GEMM: G = (X @ W) * dis[row].
// Block: 256 threads, BM=128 rows, all M columns. K staged in BK=16 tiles.
// Thread (tx=tid&15, ty=tid>>4) computes rows {ty*4+i, 64+ty*4+i} x cols
// {tx*4+j [, 64+tx*4+j]}: an 8x8 (M=128) or 8x4 (M=64) register tile.
// Xl stored k-major [BK][BM+4] (pad -> 2-way store aliasing = free);
// Wl k-major [BK][M]. Compute reads are contiguous float4 (conflict-free).
// ---------------------------------------------------------------------------
template <int K, int M>
__global__ __launch_bounds__(256, 4) void k_gemm2(
    const float* __restrict__ X, const float* __restrict__ W,
    const float* __restrict__ dis, float* __restrict__ G, int N) {
  constexpr int BM = 128;
  constexpr int BK = 16;
  constexpr int CB = M / 64;       // column blocks per thread (2 or 1)
  constexpr int WQ = M / 4;        // float4 per W row
  __shared__ float Wl[BK][M];
  __shared__ float Xl[BK][BM + 4];

  int tid = threadIdx.x;
  int tx = tid & 15, ty = tid >> 4;
  int row0 = blockIdx.x * BM;

  float acc[8][CB * 4];
#pragma unroll
  for (int i = 0; i < 8; i++)
#pragma unroll
    for (int j = 0; j < CB * 4; j++) acc[i][j] = 0.f;

  for (int kt = 0; kt < K; kt += BK) {
    // stage W tile: rows kt..kt+15, all M cols, k-major direct
#pragma unroll
    for (int t = tid; t < BK * WQ; t += 256) {
      int krow = t / WQ, cq = t % WQ;
      *(float4*)&Wl[krow][cq * 4] =
          *(const float4*)&W[(size_t)(kt + krow) * M + cq * 4];
    }
    // stage X tile transposed: task t -> (row=t>>2, kq=t&3)
#pragma unroll
    for (int t = tid; t < BM * (BK / 4); t += 256) {
      int row = t >> 2, kq = t & 3;
      float4 v = make_float4(0.f, 0.f, 0.f, 0.f);
      if (row0 + row < N)
        v = *(const float4*)&X[(size_t)(row0 + row) * K + kt + kq * 4];
      Xl[kq * 4 + 0][row] = v.x;
      Xl[kq * 4 + 1][row] = v.y;
      Xl[kq * 4 + 2][row] = v.z;
      Xl[kq * 4 + 3][row] = v.w;
    }
    __syncthreads();
#pragma unroll
    for (int k = 0; k < BK; k++) {
      float xa[8], wa[CB * 4];
      *(float4*)&xa[0] = *(const float4*)&Xl[k][ty * 4];
      *(float4*)&xa[4] = *(const float4*)&Xl[k][64 + ty * 4];
      *(float4*)&wa[0] = *(const float4*)&Wl[k][tx * 4];
      if constexpr (CB == 2) *(float4*)&wa[4] = *(const float4*)&Wl[k][64 + tx * 4];
#pragma unroll
      for (int i = 0; i < 8; i++)
#pragma unroll
        for (int j = 0; j < CB * 4; j++) acc[i][j] += xa[i] * wa[j];
    }
    __syncthreads();
  }

  // epilogue: scale by dis[row], store float4s
#pragma unroll
  for (int rs = 0; rs < 2; rs++)
#pragma unroll
    for (int i = 0; i < 4; i++) {
      int row = row0 + rs * 64 + ty * 4 + i;
      if (row < N) {
        float dd = dis[row];
#pragma unroll
        for (int cs = 0; cs < CB; cs++) {
          float4 o;
          o.x = acc[rs * 4 + i][cs * 4 + 0] * dd;
          o.y = acc[rs * 4 + i][cs * 4 + 1] * dd;
          o.z = acc[rs * 4 + i][cs * 4 + 2] * dd;
          o.w = acc[rs * 4 + i][cs * 4 + 3] * dd;
          *(float4*)&G[(size_t)row * M + cs * 64 + tx * 4] = o;
        }
      }
    }
}

__device__ __forceinline__ float gelu_exact(float v) {
  return 0.5f * v * (1.0f + erff(v * 0.70710678118654752440f));
}

// out[d] = dis[d]*(sum_{s in CSR[d]} g[s] + g[d]) + b ; optional GELU.
// One wave (64 lanes) per node; VPL floats per lane.
template <int D, bool APPLY_GELU>
__global__ __launch_bounds__(256) void k_agg(
    const float* __restrict__ g, const int* __restrict__ off,
    const int* __restrict__ csr, const float* __restrict__ dis,
    const float* __restrict__ bias, float* __restrict__ out, int N) {
  constexpr int VPL = D / 64;  // 2 for D=128, 1 for D=64
  int wid = (blockIdx.x * 256 + threadIdx.x) >> 6;
  int lane = threadIdx.x & 63;
  if (wid >= N) return;
  int d = wid;
  float acc0, acc1 = 0.f;
  if constexpr (VPL == 2) {
    float2 s = *(const float2*)(g + (size_t)d * D + lane * 2);
    acc0 = s.x;
    acc1 = s.y;
  } else {
    acc0 = g[(size_t)d * D + lane];
  }
  int beg = off[d], end = off[d + 1];
  int j = beg;
  for (; j + 4 <= end; j += 4) {
    int s0 = csr[j], s1 = csr[j + 1], s2 = csr[j + 2], s3 = csr[j + 3];
    if constexpr (VPL == 2) {
      float2 a = *(const float2*)(g + (size_t)s0 * D + lane * 2);
      float2 b = *(const float2*)(g + (size_t)s1 * D + lane * 2);
      float2 c = *(const float2*)(g + (size_t)s2 * D + lane * 2);
      float2 e = *(const float2*)(g + (size_t)s3 * D + lane * 2);
      acc0 += a.x + b.x + c.x + e.x;
      acc1 += a.y + b.y + c.y + e.y;
    } else {
      acc0 += g[(size_t)s0 * D + lane] + g[(size_t)s1 * D + lane] +
              g[(size_t)s2 * D + lane] + g[(size_t)s3 * D + lane];
    }
  }
  for (; j < end; j++) {
    int s0 = csr[j];
    if constexpr (VPL == 2) {
      float2 a = *(const float2*)(g + (size_t)s0 * D + lane * 2);
      acc0 += a.x;
      acc1 += a.y;
    } else {
      acc0 += g[(size_t)s0 * D + lane];
    }
  }
  float dd = dis[d];
  if constexpr (VPL == 2) {
    int c0 = lane * 2;
    float v0 = acc0 * dd + bias[c0];
    float v1 = acc1 * dd + bias[c0 + 1];
    if constexpr (APPLY_GELU) {
      v0 = gelu_exact(v0);
      v1 = gelu_exact(v1);
    }
    float2 o = {v0, v1};
    *(float2*)(out + (size_t)d * D + c0) = o;
  } else {
    float v0 = acc0 * dd + bias[lane];
    if constexpr (APPLY_GELU) v0 = gelu_exact(v0);
    out[(size_t)d * D + lane] = v0;
  }
}

extern "C" void kernel_launch(void* const* d_in, const int* in_sizes, int n_in,
                              void* d_out, int out_size, void* d_ws,
                              size_t ws_size, hipStream_t stream) {
  const float* x = (const float*)d_in[0];
  const int* ei = (const int*)d_in[1];
  const float* W1 = (const float*)d_in[2];
  const float* b1 = (const float*)d_in[3];
  const float* W2 = (const float*)d_in[4];
  const float* b2 = (const float*)d_in[5];
  const float* W3 = (const float*)d_in[6];
  const float* b3 = (const float*)d_in[7];
  float* out = (float*)d_out;

  const int N = in_sizes[0] / 64;
  const int E = in_sizes[1] / 2;

  char* p = (char*)d_ws;
  auto alloc = [&](size_t bytes) {
    char* r = p;
    p += (bytes + 255) & ~(size_t)255;
    return r;
  };
  float* dis = (float*)alloc((size_t)N * 4);
  int* cnt = (int*)alloc((size_t)N * 4);
  int* off = (int*)alloc((size_t)(N + 1) * 4);
  int* cursor = (int*)alloc((size_t)N * 4);
  int* bsum = (int*)alloc(4096);
  int* flag = (int*)alloc(256);
  int* csr = (int*)alloc((size_t)E * 4);
  float* bufA = (float*)alloc((size_t)N * 128 * 4);
  float* bufB = (float*)alloc((size_t)N * 128 * 4);

  const int NB = (N + 1023) / 1024;

  k_detect<<<1, 256, 0, stream>>>(ei, flag);
  k_zero<<<(N + 255) / 256, 256, 0, stream>>>(cnt, N);
  k_count<<<(E + 255) / 256, 256, 0, stream>>>(ei, cnt, E, flag);
  k_dis<<<(N + 255) / 256, 256, 0, stream>>>(cnt, dis, N);
  k_scan1<<<NB, 256, 0, stream>>>(cnt, off, bsum, N);
  k_scan2<<<1, 256, 0, stream>>>(bsum, NB);
  k_scan3<<<(N + 255) / 256, 256, 0, stream>>>(off, bsum, cursor, N, E);
  k_fill<<<(E + 255) / 256, 256, 0, stream>>>(ei, cursor, csr, E, flag);

  const int gemm_blocks = (N + 127) / 128;
  const int agg_blocks = (N + 3) / 4;  // 4 waves / block, 1 wave / node

  // layer 1: x[N,64] @ W1[64,128] -> gelu(agg + b1)
  k_gemm2<64, 128><<<gemm_blocks, 256, 0, stream>>>(x, W1, dis, bufA, N);
  k_agg<128, true><<<agg_blocks, 256, 0, stream>>>(bufA, off, csr, dis, b1, bufB, N);
  // layer 2: [N,128] @ W2[128,128]
  k_gemm2<128, 128><<<gemm_blocks, 256, 0, stream>>>(bufB, W2, dis, bufA, N);
  k_agg<128, true><<<agg_blocks, 256, 0, stream>>>(bufA, off, csr, dis, b2, bufB, N);
  // layer 3: [N,128] @ W3[128,64] -> agg + b3 (no gelu)
  k_gemm2<128, 64><<<gemm_blocks, 256, 0, stream>>>(bufB, W3, dis, bufA, N);
  k_agg<64, false><<<agg_blocks, 256, 0, stream>>>(bufA, off, csr, dis, b3, out, N);
}

// Round 3
// 514.879 us; speedup vs baseline: 1.4188x; 1.2367x over previous
//
#include <hip/hip_runtime.h>
#include <cstdint>
#include <cstddef>

// ---------------------------------------------------------------------------
// GCN 3-layer forward on MI355X.
// Pipeline: detect idx dtype -> bucket-partition edges by dst (radix-style,
// LDS histograms + 2-level scan + packed scatter) -> per-bucket degree count
// + CSR fill with LDS atomics -> 3x [reg-tiled GEMM(+dis) -> CSR agg
// (+dis +bias +gelu)].
// R2: replaced random-scatter k_fill/k_count (105MB write amplification,
// 130us) with dst-range bucketing: all scattered writes now land in
// LDS/L2-local windows.
// ---------------------------------------------------------------------------

#define CHUNK 16384   // edges per partition block
#define BSHIFT 7      // bucket = dst >> 7  (128 nodes / bucket)
#define BSZ 128

__device__ __forceinline__ int eload(const int* ei, int elem, int is64) {
  return is64 ? ei[2 * elem] : ei[elem];
}

// Detect int64 vs int32 storage: for int64, high words of the first 1024
// elements are all zero (values in [0, N) < 2^31).
__global__ void k_detect(const int* __restrict__ ei, int* __restrict__ flag) {
  __shared__ int sh[256];
  int tid = threadIdx.x;
  int o = 0;
  for (int i = tid; i < 1024; i += 256) o |= ei[2 * i + 1];
  sh[tid] = o;
  __syncthreads();
  for (int s = 128; s > 0; s >>= 1) {
    if (tid < s) sh[tid] |= sh[tid + s];
    __syncthreads();
  }
  if (tid == 0) *flag = (sh[0] == 0) ? 1 : 0;
}

// per-chunk LDS histogram over dst buckets; hist is bucket-major [P][NBLK]
__global__ __launch_bounds__(256) void k_hist(const int* __restrict__ ei,
                                              int* __restrict__ hist, int E,
                                              int N, int NBLK,
                                              const int* __restrict__ flag) {
  __shared__ int lh[1024];
  int tid = threadIdx.x;
  int P = (N + BSZ - 1) >> BSHIFT;
  for (int i = tid; i < P; i += 256) lh[i] = 0;
  __syncthreads();
  int is64 = *flag;
  int e0 = blockIdx.x * CHUNK;
  int e1 = min(e0 + CHUNK, E);
  for (int e = e0 + tid; e < e1; e += 256) {
    int d = eload(ei, E + e, is64);
    atomicAdd(&lh[d >> BSHIFT], 1);
  }
  __syncthreads();
  for (int b = tid; b < P; b += 256) hist[b * NBLK + blockIdx.x] = lh[b];
}

// ---- generic 2-level exclusive scan (1024 elems / block) ----
__global__ __launch_bounds__(256) void k_scanA(const int* __restrict__ in,
                                               int* __restrict__ out,
                                               int* __restrict__ bsum, int n) {
  __shared__ int sh[256];
  int tid = threadIdx.x;
  int base = blockIdx.x * 1024 + tid * 4;
  int v0 = (base + 0 < n) ? in[base + 0] : 0;
  int v1 = (base + 1 < n) ? in[base + 1] : 0;
  int v2 = (base + 2 < n) ? in[base + 2] : 0;
  int v3 = (base + 3 < n) ? in[base + 3] : 0;
  int tsum = v0 + v1 + v2 + v3;
  sh[tid] = tsum;
  __syncthreads();
  for (int o = 1; o < 256; o <<= 1) {
    int x = (tid >= o) ? sh[tid - o] : 0;
    __syncthreads();
    sh[tid] += x;
    __syncthreads();
  }
  int excl = sh[tid] - tsum;
  if (base + 0 < n) out[base + 0] = excl;
  if (base + 1 < n) out[base + 1] = excl + v0;
  if (base + 2 < n) out[base + 2] = excl + v0 + v1;
  if (base + 3 < n) out[base + 3] = excl + v0 + v1 + v2;
  if (tid == 255) bsum[blockIdx.x] = sh[255];
}

__global__ __launch_bounds__(256) void k_scanB(int* __restrict__ bsum, int NB) {
  __shared__ int sh[256];
  int tid = threadIdx.x;
  int v = (tid < NB) ? bsum[tid] : 0;
  sh[tid] = v;
  __syncthreads();
  for (int o = 1; o < 256; o <<= 1) {
    int x = (tid >= o) ? sh[tid - o] : 0;
    __syncthreads();
    sh[tid] += x;
    __syncthreads();
  }
  if (tid < NB) bsum[tid] = sh[tid] - v;  // exclusive
}

__global__ __launch_bounds__(256) void k_scanC(int* __restrict__ out,
                                               const int* __restrict__ bsum,
                                               int n, int total) {
  int i = blockIdx.x * 256 + threadIdx.x;
  if (i == 0) out[n] = total;
  if (i < n) out[i] += bsum[i >> 10];
}

// scatter edges into bucket-partitioned `pairs`, packed (src<<BSHIFT)|dst_lo.
__global__ __launch_bounds__(256) void k_scatter(const int* __restrict__ ei,
                                                 const int* __restrict__ histoff,
                                                 int* __restrict__ pairs, int E,
                                                 int N, int NBLK,
                                                 const int* __restrict__ flag) {
  __shared__ int lcur[1024];
  int tid = threadIdx.x;
  int P = (N + BSZ - 1) >> BSHIFT;
  for (int b = tid; b < P; b += 256)
    lcur[b] = histoff[b * NBLK + blockIdx.x];
  __syncthreads();
  int is64 = *flag;
  int e0 = blockIdx.x * CHUNK;
  int e1 = min(e0 + CHUNK, E);
  for (int e = e0 + tid; e < e1; e += 256) {
    int s = eload(ei, e, is64);
    int d = eload(ei, E + e, is64);
    int pos = atomicAdd(&lcur[d >> BSHIFT], 1);
    pairs[pos] = (s << BSHIFT) | (d & (BSZ - 1));
  }
}

// per-bucket degree count via LDS histogram; coalesced cnt write.
__global__ __launch_bounds__(256) void k_cnt_bucket(
    const int* __restrict__ pairs, const int* __restrict__ histoff,
    int* __restrict__ cnt, int E, int N, int NBLK) {
  __shared__ int lc[BSZ];
  int tid = threadIdx.x;
  int b = blockIdx.x;
  if (tid < BSZ) lc[tid] = 0;
  __syncthreads();
  int s0 = histoff[b * NBLK];
  int s1 = histoff[(b + 1) * NBLK];
  for (int i = s0 + tid; i < s1; i += 256)
    atomicAdd(&lc[pairs[i] & (BSZ - 1)], 1);
  __syncthreads();
  int node = (b << BSHIFT) + tid;
  if (tid < BSZ && node < N) cnt[node] = lc[tid];
}

__global__ __launch_bounds__(256) void k_dis(const int* __restrict__ cnt,
                                             float* __restrict__ dis, int N) {
  int i = blockIdx.x * 256 + threadIdx.x;
  if (i < N) dis[i] = rsqrtf((float)(cnt[i] + 1));  // +1 self loop
}

// per-bucket CSR fill: LDS cursors (init from off), csr writes in ~8KB window.
__global__ __launch_bounds__(256) void k_fill_bucket(
    const int* __restrict__ pairs, const int* __restrict__ histoff,
    const int* __restrict__ off, int* __restrict__ csr, int E, int N,
    int NBLK) {
  __shared__ int lcur[BSZ];
  int tid = threadIdx.x;
  int b = blockIdx.x;
  int node = (b << BSHIFT) + tid;
  if (tid < BSZ) lcur[tid] = (node < N) ? off[node] : 0;
  __syncthreads();
  int s0 = histoff[b * NBLK];
  int s1 = histoff[(b + 1) * NBLK];
  for (int i = s0 + tid; i < s1; i += 256) {
    int pk = pairs[i];
    int pos = atomicAdd(&lcur[pk & (BSZ - 1)], 1);
    csr[pos] = pk >> BSHIFT;
  }
}

// ---------------------------------------------------------------------------
// Register-tiled GEMM: G = (X @ W) * dis[row].  (unchanged from R1)
// ---------------------------------------------------------------------------
template <int K, int M>
__global__ __launch_bounds__(256, 4) void k_gemm2(
    const float* __restrict__ X, const float* __restrict__ W,
    const float* __restrict__ dis, float* __restrict__ G, int N) {
  constexpr int BM = 128;
  constexpr int BK = 16;
  constexpr int CB = M / 64;
  constexpr int WQ = M / 4;
  __shared__ float Wl[BK][M];
  __shared__ float Xl[BK][BM + 4];

  int tid = threadIdx.x;
  int tx = tid & 15, ty = tid >> 4;
  int row0 = blockIdx.x * BM;

  float acc[8][CB * 4];
#pragma unroll
  for (int i = 0; i < 8; i++)
#pragma unroll
    for (int j = 0; j < CB * 4; j++) acc[i][j] = 0.f;

  for (int kt = 0; kt < K; kt += BK) {
#pragma unroll
    for (int t = tid; t < BK * WQ; t += 256) {
      int krow = t / WQ, cq = t % WQ;
      *(float4*)&Wl[krow][cq * 4] =
          *(const float4*)&W[(size_t)(kt + krow) * M + cq * 4];
    }
#pragma unroll
    for (int t = tid; t < BM * (BK / 4); t += 256) {
      int row = t >> 2, kq = t & 3;
      float4 v = make_float4(0.f, 0.f, 0.f, 0.f);
      if (row0 + row < N)
        v = *(const float4*)&X[(size_t)(row0 + row) * K + kt + kq * 4];
      Xl[kq * 4 + 0][row] = v.x;
      Xl[kq * 4 + 1][row] = v.y;
      Xl[kq * 4 + 2][row] = v.z;
      Xl[kq * 4 + 3][row] = v.w;
    }
    __syncthreads();
#pragma unroll
    for (int k = 0; k < BK; k++) {
      float xa[8], wa[CB * 4];
      *(float4*)&xa[0] = *(const float4*)&Xl[k][ty * 4];
      *(float4*)&xa[4] = *(const float4*)&Xl[k][64 + ty * 4];
      *(float4*)&wa[0] = *(const float4*)&Wl[k][tx * 4];
      if constexpr (CB == 2) *(float4*)&wa[4] = *(const float4*)&Wl[k][64 + tx * 4];
#pragma unroll
      for (int i = 0; i < 8; i++)
#pragma unroll
        for (int j = 0; j < CB * 4; j++) acc[i][j] += xa[i] * wa[j];
    }
    __syncthreads();
  }

#pragma unroll
  for (int rs = 0; rs < 2; rs++)
#pragma unroll
    for (int i = 0; i < 4; i++) {
      int row = row0 + rs * 64 + ty * 4 + i;
      if (row < N) {
        float dd = dis[row];
#pragma unroll
        for (int cs = 0; cs < CB; cs++) {
          float4 o;
          o.x = acc[rs * 4 + i][cs * 4 + 0] * dd;
          o.y = acc[rs * 4 + i][cs * 4 + 1] * dd;
          o.z = acc[rs * 4 + i][cs * 4 + 2] * dd;
          o.w = acc[rs * 4 + i][cs * 4 + 3] * dd;
          *(float4*)&G[(size_t)row * M + cs * 64 + tx * 4] = o;
        }
      }
    }
}

__device__ __forceinline__ float gelu_exact(float v) {
  return 0.5f * v * (1.0f + erff(v * 0.70710678118654752440f));
}

// out[d] = dis[d]*(sum_{s in CSR[d]} g[s] + g[d]) + b ; optional GELU.
template <int D, bool APPLY_GELU>
__global__ __launch_bounds__(256) void k_agg(
    const float* __restrict__ g, const int* __restrict__ off,
    const int* __restrict__ csr, const float* __restrict__ dis,
    const float* __restrict__ bias, float* __restrict__ out, int N) {
  constexpr int VPL = D / 64;
  int wid = (blockIdx.x * 256 + threadIdx.x) >> 6;
  int lane = threadIdx.x & 63;
  if (wid >= N) return;
  int d = wid;
  float acc0, acc1 = 0.f;
  if constexpr (VPL == 2) {
    float2 s = *(const float2*)(g + (size_t)d * D + lane * 2);
    acc0 = s.x;
    acc1 = s.y;
  } else {
    acc0 = g[(size_t)d * D + lane];
  }
  int beg = off[d], end = off[d + 1];
  int j = beg;
  for (; j + 4 <= end; j += 4) {
    int s0 = csr[j], s1 = csr[j + 1], s2 = csr[j + 2], s3 = csr[j + 3];
    if constexpr (VPL == 2) {
      float2 a = *(const float2*)(g + (size_t)s0 * D + lane * 2);
      float2 b = *(const float2*)(g + (size_t)s1 * D + lane * 2);
      float2 c = *(const float2*)(g + (size_t)s2 * D + lane * 2);
      float2 e = *(const float2*)(g + (size_t)s3 * D + lane * 2);
      acc0 += a.x + b.x + c.x + e.x;
      acc1 += a.y + b.y + c.y + e.y;
    } else {
      acc0 += g[(size_t)s0 * D + lane] + g[(size_t)s1 * D + lane] +
              g[(size_t)s2 * D + lane] + g[(size_t)s3 * D + lane];
    }
  }
  for (; j < end; j++) {
    int s0 = csr[j];
    if constexpr (VPL == 2) {
      float2 a = *(const float2*)(g + (size_t)s0 * D + lane * 2);
      acc0 += a.x;
      acc1 += a.y;
    } else {
      acc0 += g[(size_t)s0 * D + lane];
    }
  }
  float dd = dis[d];
  if constexpr (VPL == 2) {
    int c0 = lane * 2;
    float v0 = acc0 * dd + bias[c0];
    float v1 = acc1 * dd + bias[c0 + 1];
    if constexpr (APPLY_GELU) {
      v0 = gelu_exact(v0);
      v1 = gelu_exact(v1);
    }
    float2 o = {v0, v1};
    *(float2*)(out + (size_t)d * D + c0) = o;
  } else {
    float v0 = acc0 * dd + bias[lane];
    if constexpr (APPLY_GELU) v0 = gelu_exact(v0);
    out[(size_t)d * D + lane] = v0;
  }
}

extern "C" void kernel_launch(void* const* d_in, const int* in_sizes, int n_in,
                              void* d_out, int out_size, void* d_ws,
                              size_t ws_size, hipStream_t stream) {
  const float* x = (const float*)d_in[0];
  const int* ei = (const int*)d_in[1];
  const float* W1 = (const float*)d_in[2];
  const float* b1 = (const float*)d_in[3];
  const float* W2 = (const float*)d_in[4];
  const float* b2 = (const float*)d_in[5];
  const float* W3 = (const float*)d_in[6];
  const float* b3 = (const float*)d_in[7];
  float* out = (float*)d_out;

  const int N = in_sizes[0] / 64;
  const int E = in_sizes[1] / 2;

  const int NBLK = (E + CHUNK - 1) / CHUNK;          // partition chunks
  const int P = (N + BSZ - 1) >> BSHIFT;             // dst buckets
  const int HT = P * NBLK;                           // histogram entries

  char* p = (char*)d_ws;
  auto alloc = [&](size_t bytes) {
    char* r = p;
    p += (bytes + 255) & ~(size_t)255;
    return r;
  };
  float* dis = (float*)alloc((size_t)N * 4);
  int* cnt = (int*)alloc((size_t)N * 4);
  int* off = (int*)alloc((size_t)(N + 1) * 4);
  int* bsumH = (int*)alloc(1024);
  int* bsumN = (int*)alloc(1024);
  int* flag = (int*)alloc(256);
  int* hist = (int*)alloc((size_t)(HT + 1) * 4);
  int* histoff = (int*)alloc((size_t)(HT + 1) * 4);
  int* pairs = (int*)alloc((size_t)E * 4);
  int* csr = (int*)alloc((size_t)E * 4);
  float* bufA = (float*)alloc((size_t)N * 128 * 4);
  float* bufB = (float*)alloc((size_t)N * 128 * 4);

  const int NBH = (HT + 1023) / 1024;
  const int NBN = (N + 1023) / 1024;

  k_detect<<<1, 256, 0, stream>>>(ei, flag);
  // partition edges by dst bucket
  k_hist<<<NBLK, 256, 0, stream>>>(ei, hist, E, N, NBLK, flag);
  k_scanA<<<NBH, 256, 0, stream>>>(hist, histoff, bsumH, HT);
  k_scanB<<<1, 256, 0, stream>>>(bsumH, NBH);
  k_scanC<<<(HT + 255) / 256, 256, 0, stream>>>(histoff, bsumH, HT, E);
  k_scatter<<<NBLK, 256, 0, stream>>>(ei, histoff, pairs, E, N, NBLK, flag);
  // per-node degrees + norm + CSR
  k_cnt_bucket<<<P, 256, 0, stream>>>(pairs, histoff, cnt, E, N, NBLK);
  k_dis<<<(N + 255) / 256, 256, 0, stream>>>(cnt, dis, N);
  k_scanA<<<NBN, 256, 0, stream>>>(cnt, off, bsumN, N);
  k_scanB<<<1, 256, 0, stream>>>(bsumN, NBN);
  k_scanC<<<(N + 255) / 256, 256, 0, stream>>>(off, bsumN, N, E);
  k_fill_bucket<<<P, 256, 0, stream>>>(pairs, histoff, off, csr, E, N, NBLK);

  const int gemm_blocks = (N + 127) / 128;
  const int agg_blocks = (N + 3) / 4;  // 4 waves / block, 1 wave / node

  k_gemm2<64, 128><<<gemm_blocks, 256, 0, stream>>>(x, W1, dis, bufA, N);
  k_agg<128, true><<<agg_blocks, 256, 0, stream>>>(bufA, off, csr, dis, b1, bufB, N);
  k_gemm2<128, 128><<<gemm_blocks, 256, 0, stream>>>(bufB, W2, dis, bufA, N);
  k_agg<128, true><<<agg_blocks, 256, 0, stream>>>(bufA, off, csr, dis, b2, bufB, N);
  k_gemm2<128, 64><<<gemm_blocks, 256, 0, stream>>>(bufB, W3, dis, bufA, N);
  k_agg<64, false><<<agg_blocks, 256, 0, stream>>>(bufA, off, csr, dis, b3, out, N);
}

// Round 4
// 512.302 us; speedup vs baseline: 1.4259x; 1.0050x over previous
//
#include <hip/hip_runtime.h>
#include <cstdint>
#include <cstddef>

// ---------------------------------------------------------------------------
// GCN 3-layer forward on MI355X.
// Pipeline: detect idx dtype -> bucket-partition edges by dst -> per-bucket
// degree count + CSR fill (LDS atomics) -> layers.
// R3: layer 1 uses A(XW) = (AX)W — aggregate x at D=64 (256B/edge instead of
// 512B/edge), then GEMM 64->128 with fused bias+gelu epilogue. Layers 2,3
// keep GEMM(dis-scale) -> agg(bias[,gelu]).
// ---------------------------------------------------------------------------

#define CHUNK 16384   // edges per partition block
#define BSHIFT 7      // bucket = dst >> 7  (128 nodes / bucket)
#define BSZ 128

__device__ __forceinline__ int eload(const int* ei, int elem, int is64) {
  return is64 ? ei[2 * elem] : ei[elem];
}

// Detect int64 vs int32 storage: for int64, high words of the first 1024
// elements are all zero (values in [0, N) < 2^31).
__global__ void k_detect(const int* __restrict__ ei, int* __restrict__ flag) {
  __shared__ int sh[256];
  int tid = threadIdx.x;
  int o = 0;
  for (int i = tid; i < 1024; i += 256) o |= ei[2 * i + 1];
  sh[tid] = o;
  __syncthreads();
  for (int s = 128; s > 0; s >>= 1) {
    if (tid < s) sh[tid] |= sh[tid + s];
    __syncthreads();
  }
  if (tid == 0) *flag = (sh[0] == 0) ? 1 : 0;
}

// per-chunk LDS histogram over dst buckets; hist is bucket-major [P][NBLK]
__global__ __launch_bounds__(256) void k_hist(const int* __restrict__ ei,
                                              int* __restrict__ hist, int E,
                                              int N, int NBLK,
                                              const int* __restrict__ flag) {
  __shared__ int lh[1024];
  int tid = threadIdx.x;
  int P = (N + BSZ - 1) >> BSHIFT;
  for (int i = tid; i < P; i += 256) lh[i] = 0;
  __syncthreads();
  int is64 = *flag;
  int e0 = blockIdx.x * CHUNK;
  int e1 = min(e0 + CHUNK, E);
  for (int e = e0 + tid; e < e1; e += 256) {
    int d = eload(ei, E + e, is64);
    atomicAdd(&lh[d >> BSHIFT], 1);
  }
  __syncthreads();
  for (int b = tid; b < P; b += 256) hist[b * NBLK + blockIdx.x] = lh[b];
}

// ---- generic 2-level exclusive scan (1024 elems / block) ----
__global__ __launch_bounds__(256) void k_scanA(const int* __restrict__ in,
                                               int* __restrict__ out,
                                               int* __restrict__ bsum, int n) {
  __shared__ int sh[256];
  int tid = threadIdx.x;
  int base = blockIdx.x * 1024 + tid * 4;
  int v0 = (base + 0 < n) ? in[base + 0] : 0;
  int v1 = (base + 1 < n) ? in[base + 1] : 0;
  int v2 = (base + 2 < n) ? in[base + 2] : 0;
  int v3 = (base + 3 < n) ? in[base + 3] : 0;
  int tsum = v0 + v1 + v2 + v3;
  sh[tid] = tsum;
  __syncthreads();
  for (int o = 1; o < 256; o <<= 1) {
    int x = (tid >= o) ? sh[tid - o] : 0;
    __syncthreads();
    sh[tid] += x;
    __syncthreads();
  }
  int excl = sh[tid] - tsum;
  if (base + 0 < n) out[base + 0] = excl;
  if (base + 1 < n) out[base + 1] = excl + v0;
  if (base + 2 < n) out[base + 2] = excl + v0 + v1;
  if (base + 3 < n) out[base + 3] = excl + v0 + v1 + v2;
  if (tid == 255) bsum[blockIdx.x] = sh[255];
}

__global__ __launch_bounds__(256) void k_scanB(int* __restrict__ bsum, int NB) {
  __shared__ int sh[256];
  int tid = threadIdx.x;
  int v = (tid < NB) ? bsum[tid] : 0;
  sh[tid] = v;
  __syncthreads();
  for (int o = 1; o < 256; o <<= 1) {
    int x = (tid >= o) ? sh[tid - o] : 0;
    __syncthreads();
    sh[tid] += x;
    __syncthreads();
  }
  if (tid < NB) bsum[tid] = sh[tid] - v;  // exclusive
}

__global__ __launch_bounds__(256) void k_scanC(int* __restrict__ out,
                                               const int* __restrict__ bsum,
                                               int n, int total) {
  int i = blockIdx.x * 256 + threadIdx.x;
  if (i == 0) out[n] = total;
  if (i < n) out[i] += bsum[i >> 10];
}

// scatter edges into bucket-partitioned `pairs`, packed (src<<BSHIFT)|dst_lo.
__global__ __launch_bounds__(256) void k_scatter(const int* __restrict__ ei,
                                                 const int* __restrict__ histoff,
                                                 int* __restrict__ pairs, int E,
                                                 int N, int NBLK,
                                                 const int* __restrict__ flag) {
  __shared__ int lcur[1024];
  int tid = threadIdx.x;
  int P = (N + BSZ - 1) >> BSHIFT;
  for (int b = tid; b < P; b += 256)
    lcur[b] = histoff[b * NBLK + blockIdx.x];
  __syncthreads();
  int is64 = *flag;
  int e0 = blockIdx.x * CHUNK;
  int e1 = min(e0 + CHUNK, E);
  for (int e = e0 + tid; e < e1; e += 256) {
    int s = eload(ei, e, is64);
    int d = eload(ei, E + e, is64);
    int pos = atomicAdd(&lcur[d >> BSHIFT], 1);
    pairs[pos] = (s << BSHIFT) | (d & (BSZ - 1));
  }
}

// per-bucket degree count via LDS histogram; coalesced cnt write.
__global__ __launch_bounds__(256) void k_cnt_bucket(
    const int* __restrict__ pairs, const int* __restrict__ histoff,
    int* __restrict__ cnt, int E, int N, int NBLK) {
  __shared__ int lc[BSZ];
  int tid = threadIdx.x;
  int b = blockIdx.x;
  if (tid < BSZ) lc[tid] = 0;
  __syncthreads();
  int s0 = histoff[b * NBLK];
  int s1 = histoff[(b + 1) * NBLK];
  for (int i = s0 + tid; i < s1; i += 256)
    atomicAdd(&lc[pairs[i] & (BSZ - 1)], 1);
  __syncthreads();
  int node = (b << BSHIFT) + tid;
  if (tid < BSZ && node < N) cnt[node] = lc[tid];
}

__global__ __launch_bounds__(256) void k_dis(const int* __restrict__ cnt,
                                             float* __restrict__ dis, int N) {
  int i = blockIdx.x * 256 + threadIdx.x;
  if (i < N) dis[i] = rsqrtf((float)(cnt[i] + 1));  // +1 self loop
}

// xs[row] = x[row] * dis[row]  (float4 over N*64 floats)
__global__ __launch_bounds__(256) void k_scale(const float* __restrict__ x,
                                               const float* __restrict__ dis,
                                               float* __restrict__ xs, int N) {
  int i = blockIdx.x * 256 + threadIdx.x;  // float4 index
  int total = N * 16;                      // 64 floats/row = 16 float4
  if (i < total) {
    float d = dis[i >> 4];
    float4 v = ((const float4*)x)[i];
    v.x *= d; v.y *= d; v.z *= d; v.w *= d;
    ((float4*)xs)[i] = v;
  }
}

// per-bucket CSR fill: LDS cursors (init from off), csr writes in ~8KB window.
__global__ __launch_bounds__(256) void k_fill_bucket(
    const int* __restrict__ pairs, const int* __restrict__ histoff,
    const int* __restrict__ off, int* __restrict__ csr, int E, int N,
    int NBLK) {
  __shared__ int lcur[BSZ];
  int tid = threadIdx.x;
  int b = blockIdx.x;
  int node = (b << BSHIFT) + tid;
  if (tid < BSZ) lcur[tid] = (node < N) ? off[node] : 0;
  __syncthreads();
  int s0 = histoff[b * NBLK];
  int s1 = histoff[(b + 1) * NBLK];
  for (int i = s0 + tid; i < s1; i += 256) {
    int pk = pairs[i];
    int pos = atomicAdd(&lcur[pk & (BSZ - 1)], 1);
    csr[pos] = pk >> BSHIFT;
  }
}

__device__ __forceinline__ float gelu_exact(float v) {
  return 0.5f * v * (1.0f + erff(v * 0.70710678118654752440f));
}

// ---------------------------------------------------------------------------
// Register-tiled GEMM. EPI=0: G = (X@W)*dis[row]   (pre-aggregation layers)
//                      EPI=1: G = gelu((X@W)+bias) (post-aggregation, layer 1)
// ---------------------------------------------------------------------------
template <int K, int M, int EPI>
__global__ __launch_bounds__(256, 4) void k_gemm2(
    const float* __restrict__ X, const float* __restrict__ W,
    const float* __restrict__ dis, const float* __restrict__ bias,
    float* __restrict__ G, int N) {
  constexpr int BM = 128;
  constexpr int BK = 16;
  constexpr int CB = M / 64;
  constexpr int WQ = M / 4;
  __shared__ float Wl[BK][M];
  __shared__ float Xl[BK][BM + 4];

  int tid = threadIdx.x;
  int tx = tid & 15, ty = tid >> 4;
  int row0 = blockIdx.x * BM;

  float acc[8][CB * 4];
#pragma unroll
  for (int i = 0; i < 8; i++)
#pragma unroll
    for (int j = 0; j < CB * 4; j++) acc[i][j] = 0.f;

  for (int kt = 0; kt < K; kt += BK) {
#pragma unroll
    for (int t = tid; t < BK * WQ; t += 256) {
      int krow = t / WQ, cq = t % WQ;
      *(float4*)&Wl[krow][cq * 4] =
          *(const float4*)&W[(size_t)(kt + krow) * M + cq * 4];
    }
#pragma unroll
    for (int t = tid; t < BM * (BK / 4); t += 256) {
      int row = t >> 2, kq = t & 3;
      float4 v = make_float4(0.f, 0.f, 0.f, 0.f);
      if (row0 + row < N)
        v = *(const float4*)&X[(size_t)(row0 + row) * K + kt + kq * 4];
      Xl[kq * 4 + 0][row] = v.x;
      Xl[kq * 4 + 1][row] = v.y;
      Xl[kq * 4 + 2][row] = v.z;
      Xl[kq * 4 + 3][row] = v.w;
    }
    __syncthreads();
#pragma unroll
    for (int k = 0; k < BK; k++) {
      float xa[8], wa[CB * 4];
      *(float4*)&xa[0] = *(const float4*)&Xl[k][ty * 4];
      *(float4*)&xa[4] = *(const float4*)&Xl[k][64 + ty * 4];
      *(float4*)&wa[0] = *(const float4*)&Wl[k][tx * 4];
      if constexpr (CB == 2) *(float4*)&wa[4] = *(const float4*)&Wl[k][64 + tx * 4];
#pragma unroll
      for (int i = 0; i < 8; i++)
#pragma unroll
        for (int j = 0; j < CB * 4; j++) acc[i][j] += xa[i] * wa[j];
    }
    __syncthreads();
  }

#pragma unroll
  for (int rs = 0; rs < 2; rs++)
#pragma unroll
    for (int i = 0; i < 4; i++) {
      int row = row0 + rs * 64 + ty * 4 + i;
      if (row < N) {
        float dd = (EPI == 0) ? dis[row] : 0.f;
#pragma unroll
        for (int cs = 0; cs < CB; cs++) {
          float4 o;
          int c0 = cs * 64 + tx * 4;
          if constexpr (EPI == 0) {
            o.x = acc[rs * 4 + i][cs * 4 + 0] * dd;
            o.y = acc[rs * 4 + i][cs * 4 + 1] * dd;
            o.z = acc[rs * 4 + i][cs * 4 + 2] * dd;
            o.w = acc[rs * 4 + i][cs * 4 + 3] * dd;
          } else {
            o.x = gelu_exact(acc[rs * 4 + i][cs * 4 + 0] + bias[c0 + 0]);
            o.y = gelu_exact(acc[rs * 4 + i][cs * 4 + 1] + bias[c0 + 1]);
            o.z = gelu_exact(acc[rs * 4 + i][cs * 4 + 2] + bias[c0 + 2]);
            o.w = gelu_exact(acc[rs * 4 + i][cs * 4 + 3] + bias[c0 + 3]);
          }
          *(float4*)&G[(size_t)row * M + c0] = o;
        }
      }
    }
}

// out[d] = dis[d]*(sum_{s in CSR[d]} g[s] + g[d]) [+ b] [gelu]
template <int D, bool HAS_BIAS, bool HAS_GELU>
__global__ __launch_bounds__(256) void k_agg(
    const float* __restrict__ g, const int* __restrict__ off,
    const int* __restrict__ csr, const float* __restrict__ dis,
    const float* __restrict__ bias, float* __restrict__ out, int N) {
  constexpr int VPL = D / 64;
  int wid = (blockIdx.x * 256 + threadIdx.x) >> 6;
  int lane = threadIdx.x & 63;
  if (wid >= N) return;
  int d = wid;
  float acc0, acc1 = 0.f;
  if constexpr (VPL == 2) {
    float2 s = *(const float2*)(g + (size_t)d * D + lane * 2);
    acc0 = s.x;
    acc1 = s.y;
  } else {
    acc0 = g[(size_t)d * D + lane];
  }
  int beg = off[d], end = off[d + 1];
  int j = beg;
  for (; j + 4 <= end; j += 4) {
    int s0 = csr[j], s1 = csr[j + 1], s2 = csr[j + 2], s3 = csr[j + 3];
    if constexpr (VPL == 2) {
      float2 a = *(const float2*)(g + (size_t)s0 * D + lane * 2);
      float2 b = *(const float2*)(g + (size_t)s1 * D + lane * 2);
      float2 c = *(const float2*)(g + (size_t)s2 * D + lane * 2);
      float2 e = *(const float2*)(g + (size_t)s3 * D + lane * 2);
      acc0 += a.x + b.x + c.x + e.x;
      acc1 += a.y + b.y + c.y + e.y;
    } else {
      acc0 += g[(size_t)s0 * D + lane] + g[(size_t)s1 * D + lane] +
              g[(size_t)s2 * D + lane] + g[(size_t)s3 * D + lane];
    }
  }
  for (; j < end; j++) {
    int s0 = csr[j];
    if constexpr (VPL == 2) {
      float2 a = *(const float2*)(g + (size_t)s0 * D + lane * 2);
      acc0 += a.x;
      acc1 += a.y;
    } else {
      acc0 += g[(size_t)s0 * D + lane];
    }
  }
  float dd = dis[d];
  if constexpr (VPL == 2) {
    int c0 = lane * 2;
    float v0 = acc0 * dd;
    float v1 = acc1 * dd;
    if constexpr (HAS_BIAS) { v0 += bias[c0]; v1 += bias[c0 + 1]; }
    if constexpr (HAS_GELU) { v0 = gelu_exact(v0); v1 = gelu_exact(v1); }
    float2 o = {v0, v1};
    *(float2*)(out + (size_t)d * D + c0) = o;
  } else {
    float v0 = acc0 * dd;
    if constexpr (HAS_BIAS) v0 += bias[lane];
    if constexpr (HAS_GELU) v0 = gelu_exact(v0);
    out[(size_t)d * D + lane] = v0;
  }
}

extern "C" void kernel_launch(void* const* d_in, const int* in_sizes, int n_in,
                              void* d_out, int out_size, void* d_ws,
                              size_t ws_size, hipStream_t stream) {
  const float* x = (const float*)d_in[0];
  const int* ei = (const int*)d_in[1];
  const float* W1 = (const float*)d_in[2];
  const float* b1 = (const float*)d_in[3];
  const float* W2 = (const float*)d_in[4];
  const float* b2 = (const float*)d_in[5];
  const float* W3 = (const float*)d_in[6];
  const float* b3 = (const float*)d_in[7];
  float* out = (float*)d_out;

  const int N = in_sizes[0] / 64;
  const int E = in_sizes[1] / 2;

  const int NBLK = (E + CHUNK - 1) / CHUNK;
  const int P = (N + BSZ - 1) >> BSHIFT;
  const int HT = P * NBLK;

  char* p = (char*)d_ws;
  auto alloc = [&](size_t bytes) {
    char* r = p;
    p += (bytes + 255) & ~(size_t)255;
    return r;
  };
  float* dis = (float*)alloc((size_t)N * 4);
  int* cnt = (int*)alloc((size_t)N * 4);
  int* off = (int*)alloc((size_t)(N + 1) * 4);
  int* bsumH = (int*)alloc(1024);
  int* bsumN = (int*)alloc(1024);
  int* flag = (int*)alloc(256);
  int* hist = (int*)alloc((size_t)(HT + 1) * 4);
  int* histoff = (int*)alloc((size_t)(HT + 1) * 4);
  int* pairs = (int*)alloc((size_t)E * 4);
  int* csr = (int*)alloc((size_t)E * 4);
  float* bufA = (float*)alloc((size_t)N * 128 * 4);
  float* bufB = (float*)alloc((size_t)N * 128 * 4);
  float* xs = (float*)alloc((size_t)N * 64 * 4);

  const int NBH = (HT + 1023) / 1024;
  const int NBN = (N + 1023) / 1024;

  k_detect<<<1, 256, 0, stream>>>(ei, flag);
  k_hist<<<NBLK, 256, 0, stream>>>(ei, hist, E, N, NBLK, flag);
  k_scanA<<<NBH, 256, 0, stream>>>(hist, histoff, bsumH, HT);
  k_scanB<<<1, 256, 0, stream>>>(bsumH, NBH);
  k_scanC<<<(HT + 255) / 256, 256, 0, stream>>>(histoff, bsumH, HT, E);
  k_scatter<<<NBLK, 256, 0, stream>>>(ei, histoff, pairs, E, N, NBLK, flag);
  k_cnt_bucket<<<P, 256, 0, stream>>>(pairs, histoff, cnt, E, N, NBLK);
  k_dis<<<(N + 255) / 256, 256, 0, stream>>>(cnt, dis, N);
  k_scanA<<<NBN, 256, 0, stream>>>(cnt, off, bsumN, N);
  k_scanB<<<1, 256, 0, stream>>>(bsumN, NBN);
  k_scanC<<<(N + 255) / 256, 256, 0, stream>>>(off, bsumN, N, E);
  k_fill_bucket<<<P, 256, 0, stream>>>(pairs, histoff, off, csr, E, N, NBLK);

  const int gemm_blocks = (N + 127) / 128;
  const int agg_blocks = (N + 3) / 4;  // 4 waves/block, 1 wave/node

  // layer 1 (swapped): xs = x*dis; Xa = agg(xs); h1 = gelu(Xa@W1 + b1)
  k_scale<<<(N * 16 + 255) / 256, 256, 0, stream>>>(x, dis, xs, N);
  k_agg<64, false, false><<<agg_blocks, 256, 0, stream>>>(xs, off, csr, dis,
                                                          nullptr, bufB, N);
  k_gemm2<64, 128, 1><<<gemm_blocks, 256, 0, stream>>>(bufB, W1, nullptr, b1,
                                                       bufA, N);
  // layer 2: g = (h1@W2)*dis; h2 = gelu(agg(g) + b2)
  k_gemm2<128, 128, 0><<<gemm_blocks, 256, 0, stream>>>(bufA, W2, dis, nullptr,
                                                        bufB, N);
  k_agg<128, true, true><<<agg_blocks, 256, 0, stream>>>(bufB, off, csr, dis,
                                                         b2, bufA, N);
  // layer 3: g = (h2@W3)*dis; out = agg(g) + b3
  k_gemm2<128, 64, 0><<<gemm_blocks, 256, 0, stream>>>(bufA, W3, dis, nullptr,
                                                       bufB, N);
  k_agg<64, true, false><<<agg_blocks, 256, 0, stream>>>(bufB, off, csr, dis,
                                                         b3, out, N);
}

// Round 5
// 497.337 us; speedup vs baseline: 1.4688x; 1.0301x over previous
//
#include <hip/hip_runtime.h>
#include <cstdint>
#include <cstddef>

// ---------------------------------------------------------------------------
// GCN 3-layer forward on MI355X.
// Pipeline: detect idx dtype -> bucket-partition edges by dst -> per-bucket
// degree count + CSR fill (LDS atomics) -> layers.
// R3: layer 1 aggregates x at D=64 (A(XW)=(AX)W), GEMM grows bias+gelu epi.
// R4: k_agg repacked — float4 per lane, multiple nodes per wave (2 for D=128,
// 4 for D=64). Evidence: D=64 agg ran at the same speed as D=128 agg
// (~106 vs 118us) => gather-instruction bound, not byte bound. This cuts
// gather instructions per edge by 2x/4x.
// ---------------------------------------------------------------------------

#define CHUNK 16384   // edges per partition block
#define BSHIFT 7      // bucket = dst >> 7  (128 nodes / bucket)
#define BSZ 128

__device__ __forceinline__ int eload(const int* ei, int elem, int is64) {
  return is64 ? ei[2 * elem] : ei[elem];
}

// Detect int64 vs int32 storage: for int64, high words of the first 1024
// elements are all zero (values in [0, N) < 2^31).
__global__ void k_detect(const int* __restrict__ ei, int* __restrict__ flag) {
  __shared__ int sh[256];
  int tid = threadIdx.x;
  int o = 0;
  for (int i = tid; i < 1024; i += 256) o |= ei[2 * i + 1];
  sh[tid] = o;
  __syncthreads();
  for (int s = 128; s > 0; s >>= 1) {
    if (tid < s) sh[tid] |= sh[tid + s];
    __syncthreads();
  }
  if (tid == 0) *flag = (sh[0] == 0) ? 1 : 0;
}

// per-chunk LDS histogram over dst buckets; hist is bucket-major [P][NBLK]
__global__ __launch_bounds__(256) void k_hist(const int* __restrict__ ei,
                                              int* __restrict__ hist, int E,
                                              int N, int NBLK,
                                              const int* __restrict__ flag) {
  __shared__ int lh[1024];
  int tid = threadIdx.x;
  int P = (N + BSZ - 1) >> BSHIFT;
  for (int i = tid; i < P; i += 256) lh[i] = 0;
  __syncthreads();
  int is64 = *flag;
  int e0 = blockIdx.x * CHUNK;
  int e1 = min(e0 + CHUNK, E);
  for (int e = e0 + tid; e < e1; e += 256) {
    int d = eload(ei, E + e, is64);
    atomicAdd(&lh[d >> BSHIFT], 1);
  }
  __syncthreads();
  for (int b = tid; b < P; b += 256) hist[b * NBLK + blockIdx.x] = lh[b];
}

// ---- generic 2-level exclusive scan (1024 elems / block) ----
__global__ __launch_bounds__(256) void k_scanA(const int* __restrict__ in,
                                               int* __restrict__ out,
                                               int* __restrict__ bsum, int n) {
  __shared__ int sh[256];
  int tid = threadIdx.x;
  int base = blockIdx.x * 1024 + tid * 4;
  int v0 = (base + 0 < n) ? in[base + 0] : 0;
  int v1 = (base + 1 < n) ? in[base + 1] : 0;
  int v2 = (base + 2 < n) ? in[base + 2] : 0;
  int v3 = (base + 3 < n) ? in[base + 3] : 0;
  int tsum = v0 + v1 + v2 + v3;
  sh[tid] = tsum;
  __syncthreads();
  for (int o = 1; o < 256; o <<= 1) {
    int x = (tid >= o) ? sh[tid - o] : 0;
    __syncthreads();
    sh[tid] += x;
    __syncthreads();
  }
  int excl = sh[tid] - tsum;
  if (base + 0 < n) out[base + 0] = excl;
  if (base + 1 < n) out[base + 1] = excl + v0;
  if (base + 2 < n) out[base + 2] = excl + v0 + v1;
  if (base + 3 < n) out[base + 3] = excl + v0 + v1 + v2;
  if (tid == 255) bsum[blockIdx.x] = sh[255];
}

__global__ __launch_bounds__(256) void k_scanB(int* __restrict__ bsum, int NB) {
  __shared__ int sh[256];
  int tid = threadIdx.x;
  int v = (tid < NB) ? bsum[tid] : 0;
  sh[tid] = v;
  __syncthreads();
  for (int o = 1; o < 256; o <<= 1) {
    int x = (tid >= o) ? sh[tid - o] : 0;
    __syncthreads();
    sh[tid] += x;
    __syncthreads();
  }
  if (tid < NB) bsum[tid] = sh[tid] - v;  // exclusive
}

__global__ __launch_bounds__(256) void k_scanC(int* __restrict__ out,
                                               const int* __restrict__ bsum,
                                               int n, int total) {
  int i = blockIdx.x * 256 + threadIdx.x;
  if (i == 0) out[n] = total;
  if (i < n) out[i] += bsum[i >> 10];
}

// scatter edges into bucket-partitioned `pairs`, packed (src<<BSHIFT)|dst_lo.
__global__ __launch_bounds__(256) void k_scatter(const int* __restrict__ ei,
                                                 const int* __restrict__ histoff,
                                                 int* __restrict__ pairs, int E,
                                                 int N, int NBLK,
                                                 const int* __restrict__ flag) {
  __shared__ int lcur[1024];
  int tid = threadIdx.x;
  int P = (N + BSZ - 1) >> BSHIFT;
  for (int b = tid; b < P; b += 256)
    lcur[b] = histoff[b * NBLK + blockIdx.x];
  __syncthreads();
  int is64 = *flag;
  int e0 = blockIdx.x * CHUNK;
  int e1 = min(e0 + CHUNK, E);
  for (int e = e0 + tid; e < e1; e += 256) {
    int s = eload(ei, e, is64);
    int d = eload(ei, E + e, is64);
    int pos = atomicAdd(&lcur[d >> BSHIFT], 1);
    pairs[pos] = (s << BSHIFT) | (d & (BSZ - 1));
  }
}

// per-bucket degree count via LDS histogram; coalesced cnt write.
__global__ __launch_bounds__(256) void k_cnt_bucket(
    const int* __restrict__ pairs, const int* __restrict__ histoff,
    int* __restrict__ cnt, int E, int N, int NBLK) {
  __shared__ int lc[BSZ];
  int tid = threadIdx.x;
  int b = blockIdx.x;
  if (tid < BSZ) lc[tid] = 0;
  __syncthreads();
  int s0 = histoff[b * NBLK];
  int s1 = histoff[(b + 1) * NBLK];
  for (int i = s0 + tid; i < s1; i += 256)
    atomicAdd(&lc[pairs[i] & (BSZ - 1)], 1);
  __syncthreads();
  int node = (b << BSHIFT) + tid;
  if (tid < BSZ && node < N) cnt[node] = lc[tid];
}

__global__ __launch_bounds__(256) void k_dis(const int* __restrict__ cnt,
                                             float* __restrict__ dis, int N) {
  int i = blockIdx.x * 256 + threadIdx.x;
  if (i < N) dis[i] = rsqrtf((float)(cnt[i] + 1));  // +1 self loop
}

// xs[row] = x[row] * dis[row]  (float4 over N*64 floats)
__global__ __launch_bounds__(256) void k_scale(const float* __restrict__ x,
                                               const float* __restrict__ dis,
                                               float* __restrict__ xs, int N) {
  int i = blockIdx.x * 256 + threadIdx.x;  // float4 index
  int total = N * 16;                      // 64 floats/row = 16 float4
  if (i < total) {
    float d = dis[i >> 4];
    float4 v = ((const float4*)x)[i];
    v.x *= d; v.y *= d; v.z *= d; v.w *= d;
    ((float4*)xs)[i] = v;
  }
}

// per-bucket CSR fill: LDS cursors (init from off), csr writes in ~8KB window.
__global__ __launch_bounds__(256) void k_fill_bucket(
    const int* __restrict__ pairs, const int* __restrict__ histoff,
    const int* __restrict__ off, int* __restrict__ csr, int E, int N,
    int NBLK) {
  __shared__ int lcur[BSZ];
  int tid = threadIdx.x;
  int b = blockIdx.x;
  int node = (b << BSHIFT) + tid;
  if (tid < BSZ) lcur[tid] = (node < N) ? off[node] : 0;
  __syncthreads();
  int s0 = histoff[b * NBLK];
  int s1 = histoff[(b + 1) * NBLK];
  for (int i = s0 + tid; i < s1; i += 256) {
    int pk = pairs[i];
    int pos = atomicAdd(&lcur[pk & (BSZ - 1)], 1);
    csr[pos] = pk >> BSHIFT;
  }
}

__device__ __forceinline__ float gelu_exact(float v) {
  return 0.5f * v * (1.0f + erff(v * 0.70710678118654752440f));
}

// ---------------------------------------------------------------------------
// Register-tiled GEMM. EPI=0: G = (X@W)*dis[row]   (pre-aggregation layers)
//                      EPI=1: G = gelu((X@W)+bias) (post-aggregation, layer 1)
// ---------------------------------------------------------------------------
template <int K, int M, int EPI>
__global__ __launch_bounds__(256, 4) void k_gemm2(
    const float* __restrict__ X, const float* __restrict__ W,
    const float* __restrict__ dis, const float* __restrict__ bias,
    float* __restrict__ G, int N) {
  constexpr int BM = 128;
  constexpr int BK = 16;
  constexpr int CB = M / 64;
  constexpr int WQ = M / 4;
  __shared__ float Wl[BK][M];
  __shared__ float Xl[BK][BM + 4];

  int tid = threadIdx.x;
  int tx = tid & 15, ty = tid >> 4;
  int row0 = blockIdx.x * BM;

  float acc[8][CB * 4];
#pragma unroll
  for (int i = 0; i < 8; i++)
#pragma unroll
    for (int j = 0; j < CB * 4; j++) acc[i][j] = 0.f;

  for (int kt = 0; kt < K; kt += BK) {
#pragma unroll
    for (int t = tid; t < BK * WQ; t += 256) {
      int krow = t / WQ, cq = t % WQ;
      *(float4*)&Wl[krow][cq * 4] =
          *(const float4*)&W[(size_t)(kt + krow) * M + cq * 4];
    }
#pragma unroll
    for (int t = tid; t < BM * (BK / 4); t += 256) {
      int row = t >> 2, kq = t & 3;
      float4 v = make_float4(0.f, 0.f, 0.f, 0.f);
      if (row0 + row < N)
        v = *(const float4*)&X[(size_t)(row0 + row) * K + kt + kq * 4];
      Xl[kq * 4 + 0][row] = v.x;
      Xl[kq * 4 + 1][row] = v.y;
      Xl[kq * 4 + 2][row] = v.z;
      Xl[kq * 4 + 3][row] = v.w;
    }
    __syncthreads();
#pragma unroll
    for (int k = 0; k < BK; k++) {
      float xa[8], wa[CB * 4];
      *(float4*)&xa[0] = *(const float4*)&Xl[k][ty * 4];
      *(float4*)&xa[4] = *(const float4*)&Xl[k][64 + ty * 4];
      *(float4*)&wa[0] = *(const float4*)&Wl[k][tx * 4];
      if constexpr (CB == 2) *(float4*)&wa[4] = *(const float4*)&Wl[k][64 + tx * 4];
#pragma unroll
      for (int i = 0; i < 8; i++)
#pragma unroll
        for (int j = 0; j < CB * 4; j++) acc[i][j] += xa[i] * wa[j];
    }
    __syncthreads();
  }

#pragma unroll
  for (int rs = 0; rs < 2; rs++)
#pragma unroll
    for (int i = 0; i < 4; i++) {
      int row = row0 + rs * 64 + ty * 4 + i;
      if (row < N) {
        float dd = (EPI == 0) ? dis[row] : 0.f;
#pragma unroll
        for (int cs = 0; cs < CB; cs++) {
          float4 o;
          int c0 = cs * 64 + tx * 4;
          if constexpr (EPI == 0) {
            o.x = acc[rs * 4 + i][cs * 4 + 0] * dd;
            o.y = acc[rs * 4 + i][cs * 4 + 1] * dd;
            o.z = acc[rs * 4 + i][cs * 4 + 2] * dd;
            o.w = acc[rs * 4 + i][cs * 4 + 3] * dd;
          } else {
            o.x = gelu_exact(acc[rs * 4 + i][cs * 4 + 0] + bias[c0 + 0]);
            o.y = gelu_exact(acc[rs * 4 + i][cs * 4 + 1] + bias[c0 + 1]);
            o.z = gelu_exact(acc[rs * 4 + i][cs * 4 + 2] + bias[c0 + 2]);
            o.w = gelu_exact(acc[rs * 4 + i][cs * 4 + 3] + bias[c0 + 3]);
          }
          *(float4*)&G[(size_t)row * M + c0] = o;
        }
      }
    }
}

// ---------------------------------------------------------------------------
// R4 aggregation: float4 per lane, LPN = D/4 lanes per node, NPW = 64/LPN
// nodes per wave (2 for D=128, 4 for D=64). One gather instruction now
// serves NPW edges at 16B/lane. out[d] = dis[d]*(sum g[s] + g[d]) [+b][gelu]
// ---------------------------------------------------------------------------
template <int D, bool HAS_BIAS, bool HAS_GELU>
__global__ __launch_bounds__(256) void k_agg(
    const float* __restrict__ g, const int* __restrict__ off,
    const int* __restrict__ csr, const float* __restrict__ dis,
    const float* __restrict__ bias, float* __restrict__ out, int N) {
  constexpr int LPN = D / 4;       // lanes per node (float4 each)
  constexpr int NPW = 64 / LPN;    // nodes per wave
  constexpr int QD = D / 4;        // float4 per row
  int wave = (blockIdx.x * 256 + threadIdx.x) >> 6;
  int lane = threadIdx.x & 63;
  int sub = lane / LPN;
  int sl = lane & (LPN - 1);
  int node = wave * NPW + sub;
  if (node >= N) return;
  const float4* G4 = (const float4*)g;
  float4 acc = G4[(size_t)node * QD + sl];  // self loop
  int beg = off[node], end = off[node + 1];
  int j = beg;
  for (; j + 4 <= end; j += 4) {
    int s0 = csr[j], s1 = csr[j + 1], s2 = csr[j + 2], s3 = csr[j + 3];
    float4 a = G4[(size_t)s0 * QD + sl];
    float4 b = G4[(size_t)s1 * QD + sl];
    float4 c = G4[(size_t)s2 * QD + sl];
    float4 e = G4[(size_t)s3 * QD + sl];
    acc.x += a.x + b.x + c.x + e.x;
    acc.y += a.y + b.y + c.y + e.y;
    acc.z += a.z + b.z + c.z + e.z;
    acc.w += a.w + b.w + c.w + e.w;
  }
  for (; j < end; j++) {
    float4 a = G4[(size_t)csr[j] * QD + sl];
    acc.x += a.x; acc.y += a.y; acc.z += a.z; acc.w += a.w;
  }
  float dd = dis[node];
  float v0 = acc.x * dd, v1 = acc.y * dd, v2 = acc.z * dd, v3 = acc.w * dd;
  int c0 = sl * 4;
  if constexpr (HAS_BIAS) {
    float4 bb = *(const float4*)&bias[c0];
    v0 += bb.x; v1 += bb.y; v2 += bb.z; v3 += bb.w;
  }
  if constexpr (HAS_GELU) {
    v0 = gelu_exact(v0); v1 = gelu_exact(v1);
    v2 = gelu_exact(v2); v3 = gelu_exact(v3);
  }
  float4 o = {v0, v1, v2, v3};
  *(float4*)&out[(size_t)node * D + c0] = o;
}

extern "C" void kernel_launch(void* const* d_in, const int* in_sizes, int n_in,
                              void* d_out, int out_size, void* d_ws,
                              size_t ws_size, hipStream_t stream) {
  const float* x = (const float*)d_in[0];
  const int* ei = (const int*)d_in[1];
  const float* W1 = (const float*)d_in[2];
  const float* b1 = (const float*)d_in[3];
  const float* W2 = (const float*)d_in[4];
  const float* b2 = (const float*)d_in[5];
  const float* W3 = (const float*)d_in[6];
  const float* b3 = (const float*)d_in[7];
  float* out = (float*)d_out;

  const int N = in_sizes[0] / 64;
  const int E = in_sizes[1] / 2;

  const int NBLK = (E + CHUNK - 1) / CHUNK;
  const int P = (N + BSZ - 1) >> BSHIFT;
  const int HT = P * NBLK;

  char* p = (char*)d_ws;
  auto alloc = [&](size_t bytes) {
    char* r = p;
    p += (bytes + 255) & ~(size_t)255;
    return r;
  };
  float* dis = (float*)alloc((size_t)N * 4);
  int* cnt = (int*)alloc((size_t)N * 4);
  int* off = (int*)alloc((size_t)(N + 1) * 4);
  int* bsumH = (int*)alloc(1024);
  int* bsumN = (int*)alloc(1024);
  int* flag = (int*)alloc(256);
  int* hist = (int*)alloc((size_t)(HT + 1) * 4);
  int* histoff = (int*)alloc((size_t)(HT + 1) * 4);
  int* pairs = (int*)alloc((size_t)E * 4);
  int* csr = (int*)alloc((size_t)E * 4);
  float* bufA = (float*)alloc((size_t)N * 128 * 4);
  float* bufB = (float*)alloc((size_t)N * 128 * 4);
  float* xs = (float*)alloc((size_t)N * 64 * 4);

  const int NBH = (HT + 1023) / 1024;
  const int NBN = (N + 1023) / 1024;

  k_detect<<<1, 256, 0, stream>>>(ei, flag);
  k_hist<<<NBLK, 256, 0, stream>>>(ei, hist, E, N, NBLK, flag);
  k_scanA<<<NBH, 256, 0, stream>>>(hist, histoff, bsumH, HT);
  k_scanB<<<1, 256, 0, stream>>>(bsumH, NBH);
  k_scanC<<<(HT + 255) / 256, 256, 0, stream>>>(histoff, bsumH, HT, E);
  k_scatter<<<NBLK, 256, 0, stream>>>(ei, histoff, pairs, E, N, NBLK, flag);
  k_cnt_bucket<<<P, 256, 0, stream>>>(pairs, histoff, cnt, E, N, NBLK);
  k_dis<<<(N + 255) / 256, 256, 0, stream>>>(cnt, dis, N);
  k_scanA<<<NBN, 256, 0, stream>>>(cnt, off, bsumN, N);
  k_scanB<<<1, 256, 0, stream>>>(bsumN, NBN);
  k_scanC<<<(N + 255) / 256, 256, 0, stream>>>(off, bsumN, N, E);
  k_fill_bucket<<<P, 256, 0, stream>>>(pairs, histoff, off, csr, E, N, NBLK);

  const int gemm_blocks = (N + 127) / 128;
  const int agg128_blocks = (N + 7) / 8;    // 2 nodes/wave, 4 waves/block
  const int agg64_blocks = (N + 15) / 16;   // 4 nodes/wave, 4 waves/block

  // layer 1 (swapped): xs = x*dis; Xa = agg(xs); h1 = gelu(Xa@W1 + b1)
  k_scale<<<(N * 16 + 255) / 256, 256, 0, stream>>>(x, dis, xs, N);
  k_agg<64, false, false><<<agg64_blocks, 256, 0, stream>>>(xs, off, csr, dis,
                                                            nullptr, bufB, N);
  k_gemm2<64, 128, 1><<<gemm_blocks, 256, 0, stream>>>(bufB, W1, nullptr, b1,
                                                       bufA, N);
  // layer 2: g = (h1@W2)*dis; h2 = gelu(agg(g) + b2)
  k_gemm2<128, 128, 0><<<gemm_blocks, 256, 0, stream>>>(bufA, W2, dis, nullptr,
                                                        bufB, N);
  k_agg<128, true, true><<<agg128_blocks, 256, 0, stream>>>(bufB, off, csr, dis,
                                                            b2, bufA, N);
  // layer 3: g = (h2@W3)*dis; out = agg(g) + b3
  k_gemm2<128, 64, 0><<<gemm_blocks, 256, 0, stream>>>(bufA, W3, dis, nullptr,
                                                       bufB, N);
  k_agg<64, true, false><<<agg64_blocks, 256, 0, stream>>>(bufB, off, csr, dis,
                                                           b3, out, N);
}

// Round 6
// 380.400 us; speedup vs baseline: 1.9203x; 1.3074x over previous
//
#include <hip/hip_runtime.h>
#include <hip/hip_fp16.h>
#include <cstdint>
#include <cstddef>

// ---------------------------------------------------------------------------
// GCN 3-layer forward on MI355X.
// Pipeline: detect idx dtype -> bucket-partition edges by dst -> per-bucket
// degree count + CSR fill (LDS atomics) -> layers.
// R3: layer 1 aggregates x at D=64 (A(XW)=(AX)W), GEMM grows bias+gelu epi.
// R5: gather tables stored fp16. Evidence: agg FETCH_SIZE pinned at 401MB
// = 8 XCDs x 51MB table (per-XCD compulsory L2 fill of an fp32 table) across
// R3 (8B/lane) and R4 (16B/lane, half the instrs) at identical 120us -> the
// only lever is table bytes. fp16 (2^-11) keeps absmax ~4e-4 < 8.4e-4 thresh;
// bf16 (2^-9) would not. Accumulation stays fp32.
// ---------------------------------------------------------------------------

#define CHUNK 16384   // edges per partition block
#define BSHIFT 7      // bucket = dst >> 7  (128 nodes / bucket)
#define BSZ 128

__device__ __forceinline__ int eload(const int* ei, int elem, int is64) {
  return is64 ? ei[2 * elem] : ei[elem];
}

// Detect int64 vs int32 storage: for int64, high words of the first 1024
// elements are all zero (values in [0, N) < 2^31).
__global__ void k_detect(const int* __restrict__ ei, int* __restrict__ flag) {
  __shared__ int sh[256];
  int tid = threadIdx.x;
  int o = 0;
  for (int i = tid; i < 1024; i += 256) o |= ei[2 * i + 1];
  sh[tid] = o;
  __syncthreads();
  for (int s = 128; s > 0; s >>= 1) {
    if (tid < s) sh[tid] |= sh[tid + s];
    __syncthreads();
  }
  if (tid == 0) *flag = (sh[0] == 0) ? 1 : 0;
}

// per-chunk LDS histogram over dst buckets; hist is bucket-major [P][NBLK]
__global__ __launch_bounds__(256) void k_hist(const int* __restrict__ ei,
                                              int* __restrict__ hist, int E,
                                              int N, int NBLK,
                                              const int* __restrict__ flag) {
  __shared__ int lh[1024];
  int tid = threadIdx.x;
  int P = (N + BSZ - 1) >> BSHIFT;
  for (int i = tid; i < P; i += 256) lh[i] = 0;
  __syncthreads();
  int is64 = *flag;
  int e0 = blockIdx.x * CHUNK;
  int e1 = min(e0 + CHUNK, E);
  for (int e = e0 + tid; e < e1; e += 256) {
    int d = eload(ei, E + e, is64);
    atomicAdd(&lh[d >> BSHIFT], 1);
  }
  __syncthreads();
  for (int b = tid; b < P; b += 256) hist[b * NBLK + blockIdx.x] = lh[b];
}

// ---- generic 2-level exclusive scan (1024 elems / block) ----
__global__ __launch_bounds__(256) void k_scanA(const int* __restrict__ in,
                                               int* __restrict__ out,
                                               int* __restrict__ bsum, int n) {
  __shared__ int sh[256];
  int tid = threadIdx.x;
  int base = blockIdx.x * 1024 + tid * 4;
  int v0 = (base + 0 < n) ? in[base + 0] : 0;
  int v1 = (base + 1 < n) ? in[base + 1] : 0;
  int v2 = (base + 2 < n) ? in[base + 2] : 0;
  int v3 = (base + 3 < n) ? in[base + 3] : 0;
  int tsum = v0 + v1 + v2 + v3;
  sh[tid] = tsum;
  __syncthreads();
  for (int o = 1; o < 256; o <<= 1) {
    int x = (tid >= o) ? sh[tid - o] : 0;
    __syncthreads();
    sh[tid] += x;
    __syncthreads();
  }
  int excl = sh[tid] - tsum;
  if (base + 0 < n) out[base + 0] = excl;
  if (base + 1 < n) out[base + 1] = excl + v0;
  if (base + 2 < n) out[base + 2] = excl + v0 + v1;
  if (base + 3 < n) out[base + 3] = excl + v0 + v1 + v2;
  if (tid == 255) bsum[blockIdx.x] = sh[255];
}

__global__ __launch_bounds__(256) void k_scanB(int* __restrict__ bsum, int NB) {
  __shared__ int sh[256];
  int tid = threadIdx.x;
  int v = (tid < NB) ? bsum[tid] : 0;
  sh[tid] = v;
  __syncthreads();
  for (int o = 1; o < 256; o <<= 1) {
    int x = (tid >= o) ? sh[tid - o] : 0;
    __syncthreads();
    sh[tid] += x;
    __syncthreads();
  }
  if (tid < NB) bsum[tid] = sh[tid] - v;  // exclusive
}

__global__ __launch_bounds__(256) void k_scanC(int* __restrict__ out,
                                               const int* __restrict__ bsum,
                                               int n, int total) {
  int i = blockIdx.x * 256 + threadIdx.x;
  if (i == 0) out[n] = total;
  if (i < n) out[i] += bsum[i >> 10];
}

// scatter edges into bucket-partitioned `pairs`, packed (src<<BSHIFT)|dst_lo.
__global__ __launch_bounds__(256) void k_scatter(const int* __restrict__ ei,
                                                 const int* __restrict__ histoff,
                                                 int* __restrict__ pairs, int E,
                                                 int N, int NBLK,
                                                 const int* __restrict__ flag) {
  __shared__ int lcur[1024];
  int tid = threadIdx.x;
  int P = (N + BSZ - 1) >> BSHIFT;
  for (int b = tid; b < P; b += 256)
    lcur[b] = histoff[b * NBLK + blockIdx.x];
  __syncthreads();
  int is64 = *flag;
  int e0 = blockIdx.x * CHUNK;
  int e1 = min(e0 + CHUNK, E);
  for (int e = e0 + tid; e < e1; e += 256) {
    int s = eload(ei, e, is64);
    int d = eload(ei, E + e, is64);
    int pos = atomicAdd(&lcur[d >> BSHIFT], 1);
    pairs[pos] = (s << BSHIFT) | (d & (BSZ - 1));
  }
}

// per-bucket degree count via LDS histogram; coalesced cnt write.
__global__ __launch_bounds__(256) void k_cnt_bucket(
    const int* __restrict__ pairs, const int* __restrict__ histoff,
    int* __restrict__ cnt, int E, int N, int NBLK) {
  __shared__ int lc[BSZ];
  int tid = threadIdx.x;
  int b = blockIdx.x;
  if (tid < BSZ) lc[tid] = 0;
  __syncthreads();
  int s0 = histoff[b * NBLK];
  int s1 = histoff[(b + 1) * NBLK];
  for (int i = s0 + tid; i < s1; i += 256)
    atomicAdd(&lc[pairs[i] & (BSZ - 1)], 1);
  __syncthreads();
  int node = (b << BSHIFT) + tid;
  if (tid < BSZ && node < N) cnt[node] = lc[tid];
}

__global__ __launch_bounds__(256) void k_dis(const int* __restrict__ cnt,
                                             float* __restrict__ dis, int N) {
  int i = blockIdx.x * 256 + threadIdx.x;
  if (i < N) dis[i] = rsqrtf((float)(cnt[i] + 1));  // +1 self loop
}

// xs[row] = fp16(x[row] * dis[row])
__global__ __launch_bounds__(256) void k_scale(const float* __restrict__ x,
                                               const float* __restrict__ dis,
                                               __half* __restrict__ xs, int N) {
  int i = blockIdx.x * 256 + threadIdx.x;  // float4 index
  int total = N * 16;                      // 64 floats/row = 16 float4
  if (i < total) {
    float d = dis[i >> 4];
    float4 v = ((const float4*)x)[i];
    union { uint2 u; __half2 h[2]; } pk;
    pk.h[0] = __floats2half2_rn(v.x * d, v.y * d);
    pk.h[1] = __floats2half2_rn(v.z * d, v.w * d);
    ((uint2*)xs)[i] = pk.u;
  }
}

// per-bucket CSR fill: LDS cursors (init from off), csr writes in ~8KB window.
__global__ __launch_bounds__(256) void k_fill_bucket(
    const int* __restrict__ pairs, const int* __restrict__ histoff,
    const int* __restrict__ off, int* __restrict__ csr, int E, int N,
    int NBLK) {
  __shared__ int lcur[BSZ];
  int tid = threadIdx.x;
  int b = blockIdx.x;
  int node = (b << BSHIFT) + tid;
  if (tid < BSZ) lcur[tid] = (node < N) ? off[node] : 0;
  __syncthreads();
  int s0 = histoff[b * NBLK];
  int s1 = histoff[(b + 1) * NBLK];
  for (int i = s0 + tid; i < s1; i += 256) {
    int pk = pairs[i];
    int pos = atomicAdd(&lcur[pk & (BSZ - 1)], 1);
    csr[pos] = pk >> BSHIFT;
  }
}

__device__ __forceinline__ float gelu_exact(float v) {
  return 0.5f * v * (1.0f + erff(v * 0.70710678118654752440f));
}

// ---------------------------------------------------------------------------
// Register-tiled GEMM. EPI=0: G = (X@W)*dis[row]   (pre-aggregation layers)
//                      EPI=1: G = gelu((X@W)+bias) (post-aggregation, layer 1)
// F16OUT=1: store output as fp16 (it is the next gather table).
// ---------------------------------------------------------------------------
template <int K, int M, int EPI, int F16OUT>
__global__ __launch_bounds__(256, 4) void k_gemm2(
    const float* __restrict__ X, const float* __restrict__ W,
    const float* __restrict__ dis, const float* __restrict__ bias,
    void* __restrict__ Gout, int N) {
  constexpr int BM = 128;
  constexpr int BK = 16;
  constexpr int CB = M / 64;
  constexpr int WQ = M / 4;
  __shared__ float Wl[BK][M];
  __shared__ float Xl[BK][BM + 4];

  int tid = threadIdx.x;
  int tx = tid & 15, ty = tid >> 4;
  int row0 = blockIdx.x * BM;

  float acc[8][CB * 4];
#pragma unroll
  for (int i = 0; i < 8; i++)
#pragma unroll
    for (int j = 0; j < CB * 4; j++) acc[i][j] = 0.f;

  for (int kt = 0; kt < K; kt += BK) {
#pragma unroll
    for (int t = tid; t < BK * WQ; t += 256) {
      int krow = t / WQ, cq = t % WQ;
      *(float4*)&Wl[krow][cq * 4] =
          *(const float4*)&W[(size_t)(kt + krow) * M + cq * 4];
    }
#pragma unroll
    for (int t = tid; t < BM * (BK / 4); t += 256) {
      int row = t >> 2, kq = t & 3;
      float4 v = make_float4(0.f, 0.f, 0.f, 0.f);
      if (row0 + row < N)
        v = *(const float4*)&X[(size_t)(row0 + row) * K + kt + kq * 4];
      Xl[kq * 4 + 0][row] = v.x;
      Xl[kq * 4 + 1][row] = v.y;
      Xl[kq * 4 + 2][row] = v.z;
      Xl[kq * 4 + 3][row] = v.w;
    }
    __syncthreads();
#pragma unroll
    for (int k = 0; k < BK; k++) {
      float xa[8], wa[CB * 4];
      *(float4*)&xa[0] = *(const float4*)&Xl[k][ty * 4];
      *(float4*)&xa[4] = *(const float4*)&Xl[k][64 + ty * 4];
      *(float4*)&wa[0] = *(const float4*)&Wl[k][tx * 4];
      if constexpr (CB == 2) *(float4*)&wa[4] = *(const float4*)&Wl[k][64 + tx * 4];
#pragma unroll
      for (int i = 0; i < 8; i++)
#pragma unroll
        for (int j = 0; j < CB * 4; j++) acc[i][j] += xa[i] * wa[j];
    }
    __syncthreads();
  }

  float* Gf = (float*)Gout;
  __half* Gh = (__half*)Gout;
#pragma unroll
  for (int rs = 0; rs < 2; rs++)
#pragma unroll
    for (int i = 0; i < 4; i++) {
      int row = row0 + rs * 64 + ty * 4 + i;
      if (row < N) {
        float dd = (EPI == 0) ? dis[row] : 0.f;
#pragma unroll
        for (int cs = 0; cs < CB; cs++) {
          float4 o;
          int c0 = cs * 64 + tx * 4;
          if constexpr (EPI == 0) {
            o.x = acc[rs * 4 + i][cs * 4 + 0] * dd;
            o.y = acc[rs * 4 + i][cs * 4 + 1] * dd;
            o.z = acc[rs * 4 + i][cs * 4 + 2] * dd;
            o.w = acc[rs * 4 + i][cs * 4 + 3] * dd;
          } else {
            o.x = gelu_exact(acc[rs * 4 + i][cs * 4 + 0] + bias[c0 + 0]);
            o.y = gelu_exact(acc[rs * 4 + i][cs * 4 + 1] + bias[c0 + 1]);
            o.z = gelu_exact(acc[rs * 4 + i][cs * 4 + 2] + bias[c0 + 2]);
            o.w = gelu_exact(acc[rs * 4 + i][cs * 4 + 3] + bias[c0 + 3]);
          }
          if constexpr (F16OUT) {
            union { uint2 u; __half2 h[2]; } pk;
            pk.h[0] = __floats2half2_rn(o.x, o.y);
            pk.h[1] = __floats2half2_rn(o.z, o.w);
            *(uint2*)&Gh[(size_t)row * M + c0] = pk.u;
          } else {
            *(float4*)&Gf[(size_t)row * M + c0] = o;
          }
        }
      }
    }
}

__device__ __forceinline__ void acc8(float* a, uint4 r) {
  const __half2* h = reinterpret_cast<const __half2*>(&r);
#pragma unroll
  for (int q = 0; q < 4; q++) {
    float2 f = __half22float2(h[q]);
    a[2 * q] += f.x;
    a[2 * q + 1] += f.y;
  }
}

// ---------------------------------------------------------------------------
// fp16-table aggregation: 8 halves (16B) per lane, LPN = D/8 lanes per node,
// NPW = 64/LPN nodes per wave (4 for D=128, 8 for D=64). fp32 accumulate.
// out[d] = dis[d]*(sum g[s] + g[d]) [+b] [gelu]  (fp32 output)
// ---------------------------------------------------------------------------
template <int D, bool HAS_BIAS, bool HAS_GELU>
__global__ __launch_bounds__(256) void k_agg(
    const __half* __restrict__ g, const int* __restrict__ off,
    const int* __restrict__ csr, const float* __restrict__ dis,
    const float* __restrict__ bias, float* __restrict__ out, int N) {
  constexpr int LPN = D / 8;     // lanes per node (16B of halves each)
  constexpr int NPW = 64 / LPN;  // nodes per wave
  int wave = (blockIdx.x * 256 + threadIdx.x) >> 6;
  int lane = threadIdx.x & 63;
  int sub = lane / LPN;
  int sl = lane % LPN;
  int node = wave * NPW + sub;
  if (node >= N) return;
  const uint4* G16 = (const uint4*)g;
  float a[8];
#pragma unroll
  for (int q = 0; q < 8; q++) a[q] = 0.f;
  acc8(a, G16[(size_t)node * LPN + sl]);  // self loop
  int beg = off[node], end = off[node + 1];
  int j = beg;
  for (; j + 4 <= end; j += 4) {
    int s0 = csr[j], s1 = csr[j + 1], s2 = csr[j + 2], s3 = csr[j + 3];
    uint4 r0 = G16[(size_t)s0 * LPN + sl];
    uint4 r1 = G16[(size_t)s1 * LPN + sl];
    uint4 r2 = G16[(size_t)s2 * LPN + sl];
    uint4 r3 = G16[(size_t)s3 * LPN + sl];
    acc8(a, r0);
    acc8(a, r1);
    acc8(a, r2);
    acc8(a, r3);
  }
  for (; j < end; j++) acc8(a, G16[(size_t)csr[j] * LPN + sl]);
  float dd = dis[node];
  int c0 = sl * 8;
  float v[8];
#pragma unroll
  for (int q = 0; q < 8; q++) v[q] = a[q] * dd;
  if constexpr (HAS_BIAS) {
    float4 b0 = *(const float4*)&bias[c0];
    float4 b1 = *(const float4*)&bias[c0 + 4];
    v[0] += b0.x; v[1] += b0.y; v[2] += b0.z; v[3] += b0.w;
    v[4] += b1.x; v[5] += b1.y; v[6] += b1.z; v[7] += b1.w;
  }
  if constexpr (HAS_GELU) {
#pragma unroll
    for (int q = 0; q < 8; q++) v[q] = gelu_exact(v[q]);
  }
  float4 o0 = {v[0], v[1], v[2], v[3]};
  float4 o1 = {v[4], v[5], v[6], v[7]};
  *(float4*)&out[(size_t)node * D + c0] = o0;
  *(float4*)&out[(size_t)node * D + c0 + 4] = o1;
}

extern "C" void kernel_launch(void* const* d_in, const int* in_sizes, int n_in,
                              void* d_out, int out_size, void* d_ws,
                              size_t ws_size, hipStream_t stream) {
  const float* x = (const float*)d_in[0];
  const int* ei = (const int*)d_in[1];
  const float* W1 = (const float*)d_in[2];
  const float* b1 = (const float*)d_in[3];
  const float* W2 = (const float*)d_in[4];
  const float* b2 = (const float*)d_in[5];
  const float* W3 = (const float*)d_in[6];
  const float* b3 = (const float*)d_in[7];
  float* out = (float*)d_out;

  const int N = in_sizes[0] / 64;
  const int E = in_sizes[1] / 2;

  const int NBLK = (E + CHUNK - 1) / CHUNK;
  const int P = (N + BSZ - 1) >> BSHIFT;
  const int HT = P * NBLK;

  char* p = (char*)d_ws;
  auto alloc = [&](size_t bytes) {
    char* r = p;
    p += (bytes + 255) & ~(size_t)255;
    return r;
  };
  float* dis = (float*)alloc((size_t)N * 4);
  int* cnt = (int*)alloc((size_t)N * 4);
  int* off = (int*)alloc((size_t)(N + 1) * 4);
  int* bsumH = (int*)alloc(1024);
  int* bsumN = (int*)alloc(1024);
  int* flag = (int*)alloc(256);
  int* hist = (int*)alloc((size_t)(HT + 1) * 4);
  int* histoff = (int*)alloc((size_t)(HT + 1) * 4);
  int* pairs = (int*)alloc((size_t)E * 4);
  int* csr = (int*)alloc((size_t)E * 4);
  float* bufA = (float*)alloc((size_t)N * 128 * 4);
  float* bufB = (float*)alloc((size_t)N * 128 * 4);
  __half* xsh = (__half*)alloc((size_t)N * 64 * 2);
  __half* gh = (__half*)alloc((size_t)N * 128 * 2);  // fp16 gather table

  const int NBH = (HT + 1023) / 1024;
  const int NBN = (N + 1023) / 1024;

  k_detect<<<1, 256, 0, stream>>>(ei, flag);
  k_hist<<<NBLK, 256, 0, stream>>>(ei, hist, E, N, NBLK, flag);
  k_scanA<<<NBH, 256, 0, stream>>>(hist, histoff, bsumH, HT);
  k_scanB<<<1, 256, 0, stream>>>(bsumH, NBH);
  k_scanC<<<(HT + 255) / 256, 256, 0, stream>>>(histoff, bsumH, HT, E);
  k_scatter<<<NBLK, 256, 0, stream>>>(ei, histoff, pairs, E, N, NBLK, flag);
  k_cnt_bucket<<<P, 256, 0, stream>>>(pairs, histoff, cnt, E, N, NBLK);
  k_dis<<<(N + 255) / 256, 256, 0, stream>>>(cnt, dis, N);
  k_scanA<<<NBN, 256, 0, stream>>>(cnt, off, bsumN, N);
  k_scanB<<<1, 256, 0, stream>>>(bsumN, NBN);
  k_scanC<<<(N + 255) / 256, 256, 0, stream>>>(off, bsumN, N, E);
  k_fill_bucket<<<P, 256, 0, stream>>>(pairs, histoff, off, csr, E, N, NBLK);

  const int gemm_blocks = (N + 127) / 128;
  const int agg128_blocks = (N + 15) / 16;  // 4 nodes/wave, 4 waves/block
  const int agg64_blocks = (N + 31) / 32;   // 8 nodes/wave, 4 waves/block

  // layer 1 (swapped): xs = fp16(x*dis); Xa = agg(xs); h1 = gelu(Xa@W1 + b1)
  k_scale<<<(N * 16 + 255) / 256, 256, 0, stream>>>(x, dis, xsh, N);
  k_agg<64, false, false><<<agg64_blocks, 256, 0, stream>>>(xsh, off, csr, dis,
                                                            nullptr, bufB, N);
  k_gemm2<64, 128, 1, 0><<<gemm_blocks, 256, 0, stream>>>(bufB, W1, nullptr,
                                                          b1, (void*)bufA, N);
  // layer 2: g = fp16((h1@W2)*dis); h2 = gelu(agg(g) + b2)
  k_gemm2<128, 128, 0, 1><<<gemm_blocks, 256, 0, stream>>>(bufA, W2, dis,
                                                           nullptr, (void*)gh, N);
  k_agg<128, true, true><<<agg128_blocks, 256, 0, stream>>>(gh, off, csr, dis,
                                                            b2, bufB, N);
  // layer 3: g = fp16((h2@W3)*dis); out = agg(g) + b3
  k_gemm2<128, 64, 0, 1><<<gemm_blocks, 256, 0, stream>>>(bufB, W3, dis,
                                                          nullptr, (void*)gh, N);
  k_agg<64, true, false><<<agg64_blocks, 256, 0, stream>>>(gh, off, csr, dis,
                                                           b3, out, N);
}

// Round 7
// 329.220 us; speedup vs baseline: 2.2189x; 1.1555x over previous
//
#include <hip/hip_runtime.h>
#include <hip/hip_fp16.h>
#include <cstdint>
#include <cstddef>

// ---------------------------------------------------------------------------
// GCN 3-layer forward on MI355X.
// Pipeline: detect idx dtype -> bucket-partition edges by dst -> fused
// per-bucket {degree, local scan -> off/dis, CSR fill} -> layers.
// R3: layer 1 aggregates x at D=64 (A(XW)=(AX)W).
// R5: gather tables fp16 (FETCH floor = 8 XCDs x table bytes).
// R6: GEMM BM 128->64 (grid 782->1563; occupancy was capped at 3 blocks/CU
// by grid size, latency-bound at 22% VALUBusy); fused build tail.
// ---------------------------------------------------------------------------

#define CHUNK 16384   // edges per partition block
#define BSHIFT 7      // bucket = dst >> 7  (128 nodes / bucket)
#define BSZ 128

__device__ __forceinline__ int eload(const int* ei, int elem, int is64) {
  return is64 ? ei[2 * elem] : ei[elem];
}

// Detect int64 vs int32 storage: for int64, high words of the first 1024
// elements are all zero (values in [0, N) < 2^31).
__global__ void k_detect(const int* __restrict__ ei, int* __restrict__ flag) {
  __shared__ int sh[256];
  int tid = threadIdx.x;
  int o = 0;
  for (int i = tid; i < 1024; i += 256) o |= ei[2 * i + 1];
  sh[tid] = o;
  __syncthreads();
  for (int s = 128; s > 0; s >>= 1) {
    if (tid < s) sh[tid] |= sh[tid + s];
    __syncthreads();
  }
  if (tid == 0) *flag = (sh[0] == 0) ? 1 : 0;
}

// per-chunk LDS histogram over dst buckets; hist is bucket-major [P][NBLK]
__global__ __launch_bounds__(256) void k_hist(const int* __restrict__ ei,
                                              int* __restrict__ hist, int E,
                                              int N, int NBLK,
                                              const int* __restrict__ flag) {
  __shared__ int lh[1024];
  int tid = threadIdx.x;
  int P = (N + BSZ - 1) >> BSHIFT;
  for (int i = tid; i < P; i += 256) lh[i] = 0;
  __syncthreads();
  int is64 = *flag;
  int e0 = blockIdx.x * CHUNK;
  int e1 = min(e0 + CHUNK, E);
  for (int e = e0 + tid; e < e1; e += 256) {
    int d = eload(ei, E + e, is64);
    atomicAdd(&lh[d >> BSHIFT], 1);
  }
  __syncthreads();
  for (int b = tid; b < P; b += 256) hist[b * NBLK + blockIdx.x] = lh[b];
}

// ---- generic 2-level exclusive scan (1024 elems / block) ----
__global__ __launch_bounds__(256) void k_scanA(const int* __restrict__ in,
                                               int* __restrict__ out,
                                               int* __restrict__ bsum, int n) {
  __shared__ int sh[256];
  int tid = threadIdx.x;
  int base = blockIdx.x * 1024 + tid * 4;
  int v0 = (base + 0 < n) ? in[base + 0] : 0;
  int v1 = (base + 1 < n) ? in[base + 1] : 0;
  int v2 = (base + 2 < n) ? in[base + 2] : 0;
  int v3 = (base + 3 < n) ? in[base + 3] : 0;
  int tsum = v0 + v1 + v2 + v3;
  sh[tid] = tsum;
  __syncthreads();
  for (int o = 1; o < 256; o <<= 1) {
    int x = (tid >= o) ? sh[tid - o] : 0;
    __syncthreads();
    sh[tid] += x;
    __syncthreads();
  }
  int excl = sh[tid] - tsum;
  if (base + 0 < n) out[base + 0] = excl;
  if (base + 1 < n) out[base + 1] = excl + v0;
  if (base + 2 < n) out[base + 2] = excl + v0 + v1;
  if (base + 3 < n) out[base + 3] = excl + v0 + v1 + v2;
  if (tid == 255) bsum[blockIdx.x] = sh[255];
}

__global__ __launch_bounds__(256) void k_scanB(int* __restrict__ bsum, int NB) {
  __shared__ int sh[256];
  int tid = threadIdx.x;
  int v = (tid < NB) ? bsum[tid] : 0;
  sh[tid] = v;
  __syncthreads();
  for (int o = 1; o < 256; o <<= 1) {
    int x = (tid >= o) ? sh[tid - o] : 0;
    __syncthreads();
    sh[tid] += x;
    __syncthreads();
  }
  if (tid < NB) bsum[tid] = sh[tid] - v;  // exclusive
}

__global__ __launch_bounds__(256) void k_scanC(int* __restrict__ out,
                                               const int* __restrict__ bsum,
                                               int n, int total) {
  int i = blockIdx.x * 256 + threadIdx.x;
  if (i == 0) out[n] = total;
  if (i < n) out[i] += bsum[i >> 10];
}

// scatter edges into bucket-partitioned `pairs`, packed (src<<BSHIFT)|dst_lo.
__global__ __launch_bounds__(256) void k_scatter(const int* __restrict__ ei,
                                                 const int* __restrict__ histoff,
                                                 int* __restrict__ pairs, int E,
                                                 int N, int NBLK,
                                                 const int* __restrict__ flag) {
  __shared__ int lcur[1024];
  int tid = threadIdx.x;
  int P = (N + BSZ - 1) >> BSHIFT;
  for (int b = tid; b < P; b += 256)
    lcur[b] = histoff[b * NBLK + blockIdx.x];
  __syncthreads();
  int is64 = *flag;
  int e0 = blockIdx.x * CHUNK;
  int e1 = min(e0 + CHUNK, E);
  for (int e = e0 + tid; e < e1; e += 256) {
    int s = eload(ei, e, is64);
    int d = eload(ei, E + e, is64);
    int pos = atomicAdd(&lcur[d >> BSHIFT], 1);
    pairs[pos] = (s << BSHIFT) | (d & (BSZ - 1));
  }
}

// ---------------------------------------------------------------------------
// Fused per-bucket build: degree count -> 128-wide local exclusive scan ->
// off[] + dis[] -> CSR fill. Offsets are bucket-local: base = histoff[b*NBLK].
// Replaces k_cnt_bucket + N-scan chain + k_dis + k_fill_bucket.
// ---------------------------------------------------------------------------
__global__ __launch_bounds__(256) void k_build_bucket(
    const int* __restrict__ pairs, const int* __restrict__ histoff,
    int* __restrict__ off, float* __restrict__ dis, int* __restrict__ csr,
    int E, int N, int NBLK, int P) {
  __shared__ int lc[BSZ];
  __shared__ int lscan[BSZ];
  __shared__ int lcur[BSZ];
  int tid = threadIdx.x;
  int b = blockIdx.x;
  if (tid < BSZ) lc[tid] = 0;
  __syncthreads();
  int s0 = histoff[b * NBLK];
  int s1 = histoff[(b + 1) * NBLK];
  for (int i = s0 + tid; i < s1; i += 256)
    atomicAdd(&lc[pairs[i] & (BSZ - 1)], 1);
  __syncthreads();
  if (tid < BSZ) lscan[tid] = lc[tid];
  __syncthreads();
#pragma unroll
  for (int o = 1; o < BSZ; o <<= 1) {
    int v = 0;
    if (tid < BSZ && tid >= o) v = lscan[tid - o];
    __syncthreads();
    if (tid < BSZ) lscan[tid] += v;
    __syncthreads();
  }
  int node = (b << BSHIFT) + tid;
  if (tid < BSZ) {
    int o_node = s0 + lscan[tid] - lc[tid];  // exclusive
    lcur[tid] = o_node;
    if (node < N) {
      off[node] = o_node;
      dis[node] = rsqrtf((float)(lc[tid] + 1));  // +1 self loop
    }
  }
  if (b == P - 1 && tid == 0) off[N] = E;
  __syncthreads();
  for (int i = s0 + tid; i < s1; i += 256) {
    int pk = pairs[i];
    int pos = atomicAdd(&lcur[pk & (BSZ - 1)], 1);
    csr[pos] = pk >> BSHIFT;
  }
}

// xs[row] = fp16(x[row] * dis[row])
__global__ __launch_bounds__(256) void k_scale(const float* __restrict__ x,
                                               const float* __restrict__ dis,
                                               __half* __restrict__ xs, int N) {
  int i = blockIdx.x * 256 + threadIdx.x;  // float4 index
  int total = N * 16;                      // 64 floats/row = 16 float4
  if (i < total) {
    float d = dis[i >> 4];
    float4 v = ((const float4*)x)[i];
    union { uint2 u; __half2 h[2]; } pk;
    pk.h[0] = __floats2half2_rn(v.x * d, v.y * d);
    pk.h[1] = __floats2half2_rn(v.z * d, v.w * d);
    ((uint2*)xs)[i] = pk.u;
  }
}

__device__ __forceinline__ float gelu_exact(float v) {
  return 0.5f * v * (1.0f + erff(v * 0.70710678118654752440f));
}

// ---------------------------------------------------------------------------
// Register-tiled GEMM, BM=64 (grid ~1563 -> ~6 blocks/CU).
// EPI=0: G = (X@W)*dis[row]; EPI=1: G = gelu((X@W)+bias).
// F16OUT=1: store fp16 (next gather table).
// Thread (tx=tid&15, ty=tid>>4): rows ty*4..+3, cols {tx*4 [,64+tx*4]}.
// ---------------------------------------------------------------------------
template <int K, int M, int EPI, int F16OUT>
__global__ __launch_bounds__(256, 6) void k_gemm3(
    const float* __restrict__ X, const float* __restrict__ W,
    const float* __restrict__ dis, const float* __restrict__ bias,
    void* __restrict__ Gout, int N) {
  constexpr int BM = 64;
  constexpr int BK = 16;
  constexpr int CB = M / 64;       // 2 (M=128) or 1 (M=64)
  constexpr int WQ = M / 4;
  __shared__ float Wl[BK][M];
  __shared__ float Xl[BK][BM + 4];

  int tid = threadIdx.x;
  int tx = tid & 15, ty = tid >> 4;  // ty 0..15
  int row0 = blockIdx.x * BM;

  float acc[4][CB * 4];
#pragma unroll
  for (int i = 0; i < 4; i++)
#pragma unroll
    for (int j = 0; j < CB * 4; j++) acc[i][j] = 0.f;

  for (int kt = 0; kt < K; kt += BK) {
    // stage W tile (k-major direct): BK*WQ float4 tasks
#pragma unroll
    for (int t = tid; t < BK * WQ; t += 256) {
      int krow = t / WQ, cq = t % WQ;
      *(float4*)&Wl[krow][cq * 4] =
          *(const float4*)&W[(size_t)(kt + krow) * M + cq * 4];
    }
    // stage X tile transposed: BM*(BK/4) = 256 tasks, 1/thread
    {
      int t = tid;
      int row = t >> 2, kq = t & 3;
      float4 v = make_float4(0.f, 0.f, 0.f, 0.f);
      if (row0 + row < N)
        v = *(const float4*)&X[(size_t)(row0 + row) * K + kt + kq * 4];
      Xl[kq * 4 + 0][row] = v.x;
      Xl[kq * 4 + 1][row] = v.y;
      Xl[kq * 4 + 2][row] = v.z;
      Xl[kq * 4 + 3][row] = v.w;
    }
    __syncthreads();
#pragma unroll
    for (int k = 0; k < BK; k++) {
      float xa[4], wa[CB * 4];
      *(float4*)&xa[0] = *(const float4*)&Xl[k][ty * 4];
      *(float4*)&wa[0] = *(const float4*)&Wl[k][tx * 4];
      if constexpr (CB == 2) *(float4*)&wa[4] = *(const float4*)&Wl[k][64 + tx * 4];
#pragma unroll
      for (int i = 0; i < 4; i++)
#pragma unroll
        for (int j = 0; j < CB * 4; j++) acc[i][j] += xa[i] * wa[j];
    }
    __syncthreads();
  }

  float* Gf = (float*)Gout;
  __half* Gh = (__half*)Gout;
#pragma unroll
  for (int i = 0; i < 4; i++) {
    int row = row0 + ty * 4 + i;
    if (row < N) {
      float dd = (EPI == 0) ? dis[row] : 0.f;
#pragma unroll
      for (int cs = 0; cs < CB; cs++) {
        float4 o;
        int c0 = cs * 64 + tx * 4;
        if constexpr (EPI == 0) {
          o.x = acc[i][cs * 4 + 0] * dd;
          o.y = acc[i][cs * 4 + 1] * dd;
          o.z = acc[i][cs * 4 + 2] * dd;
          o.w = acc[i][cs * 4 + 3] * dd;
        } else {
          o.x = gelu_exact(acc[i][cs * 4 + 0] + bias[c0 + 0]);
          o.y = gelu_exact(acc[i][cs * 4 + 1] + bias[c0 + 1]);
          o.z = gelu_exact(acc[i][cs * 4 + 2] + bias[c0 + 2]);
          o.w = gelu_exact(acc[i][cs * 4 + 3] + bias[c0 + 3]);
        }
        if constexpr (F16OUT) {
          union { uint2 u; __half2 h[2]; } pk;
          pk.h[0] = __floats2half2_rn(o.x, o.y);
          pk.h[1] = __floats2half2_rn(o.z, o.w);
          *(uint2*)&Gh[(size_t)row * M + c0] = pk.u;
        } else {
          *(float4*)&Gf[(size_t)row * M + c0] = o;
        }
      }
    }
  }
}

__device__ __forceinline__ void acc8(float* a, uint4 r) {
  const __half2* h = reinterpret_cast<const __half2*>(&r);
#pragma unroll
  for (int q = 0; q < 4; q++) {
    float2 f = __half22float2(h[q]);
    a[2 * q] += f.x;
    a[2 * q + 1] += f.y;
  }
}

// ---------------------------------------------------------------------------
// fp16-table aggregation: 8 halves (16B) per lane, LPN = D/8 lanes per node,
// NPW = 64/LPN nodes per wave. fp32 accumulate, fp32 output.
// ---------------------------------------------------------------------------
template <int D, bool HAS_BIAS, bool HAS_GELU>
__global__ __launch_bounds__(256) void k_agg(
    const __half* __restrict__ g, const int* __restrict__ off,
    const int* __restrict__ csr, const float* __restrict__ dis,
    const float* __restrict__ bias, float* __restrict__ out, int N) {
  constexpr int LPN = D / 8;     // lanes per node (16B of halves each)
  constexpr int NPW = 64 / LPN;  // nodes per wave
  int wave = (blockIdx.x * 256 + threadIdx.x) >> 6;
  int lane = threadIdx.x & 63;
  int sub = lane / LPN;
  int sl = lane % LPN;
  int node = wave * NPW + sub;
  if (node >= N) return;
  const uint4* G16 = (const uint4*)g;
  float a[8];
#pragma unroll
  for (int q = 0; q < 8; q++) a[q] = 0.f;
  acc8(a, G16[(size_t)node * LPN + sl]);  // self loop
  int beg = off[node], end = off[node + 1];
  int j = beg;
  for (; j + 4 <= end; j += 4) {
    int s0 = csr[j], s1 = csr[j + 1], s2 = csr[j + 2], s3 = csr[j + 3];
    uint4 r0 = G16[(size_t)s0 * LPN + sl];
    uint4 r1 = G16[(size_t)s1 * LPN + sl];
    uint4 r2 = G16[(size_t)s2 * LPN + sl];
    uint4 r3 = G16[(size_t)s3 * LPN + sl];
    acc8(a, r0);
    acc8(a, r1);
    acc8(a, r2);
    acc8(a, r3);
  }
  for (; j < end; j++) acc8(a, G16[(size_t)csr[j] * LPN + sl]);
  float dd = dis[node];
  int c0 = sl * 8;
  float v[8];
#pragma unroll
  for (int q = 0; q < 8; q++) v[q] = a[q] * dd;
  if constexpr (HAS_BIAS) {
    float4 b0 = *(const float4*)&bias[c0];
    float4 b1 = *(const float4*)&bias[c0 + 4];
    v[0] += b0.x; v[1] += b0.y; v[2] += b0.z; v[3] += b0.w;
    v[4] += b1.x; v[5] += b1.y; v[6] += b1.z; v[7] += b1.w;
  }
  if constexpr (HAS_GELU) {
#pragma unroll
    for (int q = 0; q < 8; q++) v[q] = gelu_exact(v[q]);
  }
  float4 o0 = {v[0], v[1], v[2], v[3]};
  float4 o1 = {v[4], v[5], v[6], v[7]};
  *(float4*)&out[(size_t)node * D + c0] = o0;
  *(float4*)&out[(size_t)node * D + c0 + 4] = o1;
}

extern "C" void kernel_launch(void* const* d_in, const int* in_sizes, int n_in,
                              void* d_out, int out_size, void* d_ws,
                              size_t ws_size, hipStream_t stream) {
  const float* x = (const float*)d_in[0];
  const int* ei = (const int*)d_in[1];
  const float* W1 = (const float*)d_in[2];
  const float* b1 = (const float*)d_in[3];
  const float* W2 = (const float*)d_in[4];
  const float* b2 = (const float*)d_in[5];
  const float* W3 = (const float*)d_in[6];
  const float* b3 = (const float*)d_in[7];
  float* out = (float*)d_out;

  const int N = in_sizes[0] / 64;
  const int E = in_sizes[1] / 2;

  const int NBLK = (E + CHUNK - 1) / CHUNK;
  const int P = (N + BSZ - 1) >> BSHIFT;
  const int HT = P * NBLK;

  char* p = (char*)d_ws;
  auto alloc = [&](size_t bytes) {
    char* r = p;
    p += (bytes + 255) & ~(size_t)255;
    return r;
  };
  float* dis = (float*)alloc((size_t)N * 4);
  int* off = (int*)alloc((size_t)(N + 1) * 4);
  int* bsumH = (int*)alloc(1024);
  int* flag = (int*)alloc(256);
  int* hist = (int*)alloc((size_t)(HT + 1) * 4);
  int* histoff = (int*)alloc((size_t)(HT + 1) * 4);
  int* pairs = (int*)alloc((size_t)E * 4);
  int* csr = (int*)alloc((size_t)E * 4);
  float* bufA = (float*)alloc((size_t)N * 128 * 4);
  float* bufB = (float*)alloc((size_t)N * 128 * 4);
  __half* xsh = (__half*)alloc((size_t)N * 64 * 2);
  __half* gh = (__half*)alloc((size_t)N * 128 * 2);  // fp16 gather table

  const int NBH = (HT + 1023) / 1024;

  k_detect<<<1, 256, 0, stream>>>(ei, flag);
  k_hist<<<NBLK, 256, 0, stream>>>(ei, hist, E, N, NBLK, flag);
  k_scanA<<<NBH, 256, 0, stream>>>(hist, histoff, bsumH, HT);
  k_scanB<<<1, 256, 0, stream>>>(bsumH, NBH);
  k_scanC<<<(HT + 255) / 256, 256, 0, stream>>>(histoff, bsumH, HT, E);
  k_scatter<<<NBLK, 256, 0, stream>>>(ei, histoff, pairs, E, N, NBLK, flag);
  k_build_bucket<<<P, 256, 0, stream>>>(pairs, histoff, off, dis, csr, E, N,
                                        NBLK, P);

  const int gemm_blocks = (N + 63) / 64;
  const int agg128_blocks = (N + 15) / 16;  // 4 nodes/wave, 4 waves/block
  const int agg64_blocks = (N + 31) / 32;   // 8 nodes/wave, 4 waves/block

  // layer 1 (swapped): xs = fp16(x*dis); Xa = agg(xs); h1 = gelu(Xa@W1 + b1)
  k_scale<<<(N * 16 + 255) / 256, 256, 0, stream>>>(x, dis, xsh, N);
  k_agg<64, false, false><<<agg64_blocks, 256, 0, stream>>>(xsh, off, csr, dis,
                                                            nullptr, bufB, N);
  k_gemm3<64, 128, 1, 0><<<gemm_blocks, 256, 0, stream>>>(bufB, W1, nullptr,
                                                          b1, (void*)bufA, N);
  // layer 2: g = fp16((h1@W2)*dis); h2 = gelu(agg(g) + b2)
  k_gemm3<128, 128, 0, 1><<<gemm_blocks, 256, 0, stream>>>(bufA, W2, dis,
                                                           nullptr, (void*)gh, N);
  k_agg<128, true, true><<<agg128_blocks, 256, 0, stream>>>(gh, off, csr, dis,
                                                            b2, bufB, N);
  // layer 3: g = fp16((h2@W3)*dis); out = agg(g) + b3
  k_gemm3<128, 64, 0, 1><<<gemm_blocks, 256, 0, stream>>>(bufB, W3, dis,
                                                          nullptr, (void*)gh, N);
  k_agg<64, true, false><<<agg64_blocks, 256, 0, stream>>>(gh, off, csr, dis,
                                                           b3, out, N);
}

// Round 8
// 307.693 us; speedup vs baseline: 2.3741x; 1.0700x over previous
//
#include <hip/hip_runtime.h>
#include <hip/hip_fp16.h>
#include <cstdint>
#include <cstddef>

// ---------------------------------------------------------------------------
// GCN 3-layer forward on MI355X.
// Pipeline: detect idx dtype -> bucket-partition edges by dst -> fused
// per-bucket {degree, scan -> off/dis, CSR fill} -> layers.
// R3: layer 1 aggregates x at D=64 (A(XW)=(AX)W).
// R5: gather tables fp16 (FETCH floor = 8 XCDs x table bytes).
// R6: fused build tail. R7 evidence: agg at per-XCD fetch floor (190MB).
// R8: GEMM 512-thr 4x4 tile (full 32-wave occupancy); CHUNK 16384->4096
// (hist/scatter were 98 blocks = 0.4/CU); agg gather unroll 8.
// ---------------------------------------------------------------------------

#define CHUNK 4096    // edges per partition block
#define BSHIFT 7      // bucket = dst >> 7  (128 nodes / bucket)
#define BSZ 128

__device__ __forceinline__ int eload(const int* ei, int elem, int is64) {
  return is64 ? ei[2 * elem] : ei[elem];
}

// Detect int64 vs int32 storage: for int64, high words of the first 1024
// elements are all zero (values in [0, N) < 2^31).
__global__ void k_detect(const int* __restrict__ ei, int* __restrict__ flag) {
  __shared__ int sh[256];
  int tid = threadIdx.x;
  int o = 0;
  for (int i = tid; i < 1024; i += 256) o |= ei[2 * i + 1];
  sh[tid] = o;
  __syncthreads();
  for (int s = 128; s > 0; s >>= 1) {
    if (tid < s) sh[tid] |= sh[tid + s];
    __syncthreads();
  }
  if (tid == 0) *flag = (sh[0] == 0) ? 1 : 0;
}

// per-chunk LDS histogram over dst buckets; hist is bucket-major [P][NBLK]
__global__ __launch_bounds__(256) void k_hist(const int* __restrict__ ei,
                                              int* __restrict__ hist, int E,
                                              int N, int NBLK,
                                              const int* __restrict__ flag) {
  __shared__ int lh[1024];
  int tid = threadIdx.x;
  int P = (N + BSZ - 1) >> BSHIFT;
  for (int i = tid; i < P; i += 256) lh[i] = 0;
  __syncthreads();
  int is64 = *flag;
  int e0 = blockIdx.x * CHUNK;
  int e1 = min(e0 + CHUNK, E);
  for (int e = e0 + tid; e < e1; e += 256) {
    int d = eload(ei, E + e, is64);
    atomicAdd(&lh[d >> BSHIFT], 1);
  }
  __syncthreads();
  for (int b = tid; b < P; b += 256) hist[b * NBLK + blockIdx.x] = lh[b];
}

// ---- generic 2-level exclusive scan (1024 elems / block) ----
__global__ __launch_bounds__(256) void k_scanA(const int* __restrict__ in,
                                               int* __restrict__ out,
                                               int* __restrict__ bsum, int n) {
  __shared__ int sh[256];
  int tid = threadIdx.x;
  int base = blockIdx.x * 1024 + tid * 4;
  int v0 = (base + 0 < n) ? in[base + 0] : 0;
  int v1 = (base + 1 < n) ? in[base + 1] : 0;
  int v2 = (base + 2 < n) ? in[base + 2] : 0;
  int v3 = (base + 3 < n) ? in[base + 3] : 0;
  int tsum = v0 + v1 + v2 + v3;
  sh[tid] = tsum;
  __syncthreads();
  for (int o = 1; o < 256; o <<= 1) {
    int x = (tid >= o) ? sh[tid - o] : 0;
    __syncthreads();
    sh[tid] += x;
    __syncthreads();
  }
  int excl = sh[tid] - tsum;
  if (base + 0 < n) out[base + 0] = excl;
  if (base + 1 < n) out[base + 1] = excl + v0;
  if (base + 2 < n) out[base + 2] = excl + v0 + v1;
  if (base + 3 < n) out[base + 3] = excl + v0 + v1 + v2;
  if (tid == 255) bsum[blockIdx.x] = sh[255];
}

// exclusive scan of up to 1024 block sums, in place (4 per thread)
__global__ __launch_bounds__(256) void k_scanB(int* __restrict__ bsum, int NB) {
  __shared__ int sh[256];
  int tid = threadIdx.x;
  int base = tid * 4;
  int v0 = (base + 0 < NB) ? bsum[base + 0] : 0;
  int v1 = (base + 1 < NB) ? bsum[base + 1] : 0;
  int v2 = (base + 2 < NB) ? bsum[base + 2] : 0;
  int v3 = (base + 3 < NB) ? bsum[base + 3] : 0;
  int tsum = v0 + v1 + v2 + v3;
  sh[tid] = tsum;
  __syncthreads();
  for (int o = 1; o < 256; o <<= 1) {
    int x = (tid >= o) ? sh[tid - o] : 0;
    __syncthreads();
    sh[tid] += x;
    __syncthreads();
  }
  int excl = sh[tid] - tsum;
  if (base + 0 < NB) bsum[base + 0] = excl;
  if (base + 1 < NB) bsum[base + 1] = excl + v0;
  if (base + 2 < NB) bsum[base + 2] = excl + v0 + v1;
  if (base + 3 < NB) bsum[base + 3] = excl + v0 + v1 + v2;
}

__global__ __launch_bounds__(256) void k_scanC(int* __restrict__ out,
                                               const int* __restrict__ bsum,
                                               int n, int total) {
  int i = blockIdx.x * 256 + threadIdx.x;
  if (i == 0) out[n] = total;
  if (i < n) out[i] += bsum[i >> 10];
}

// scatter edges into bucket-partitioned `pairs`, packed (src<<BSHIFT)|dst_lo.
__global__ __launch_bounds__(256) void k_scatter(const int* __restrict__ ei,
                                                 const int* __restrict__ histoff,
                                                 int* __restrict__ pairs, int E,
                                                 int N, int NBLK,
                                                 const int* __restrict__ flag) {
  __shared__ int lcur[1024];
  int tid = threadIdx.x;
  int P = (N + BSZ - 1) >> BSHIFT;
  for (int b = tid; b < P; b += 256)
    lcur[b] = histoff[b * NBLK + blockIdx.x];
  __syncthreads();
  int is64 = *flag;
  int e0 = blockIdx.x * CHUNK;
  int e1 = min(e0 + CHUNK, E);
  for (int e = e0 + tid; e < e1; e += 256) {
    int s = eload(ei, e, is64);
    int d = eload(ei, E + e, is64);
    int pos = atomicAdd(&lcur[d >> BSHIFT], 1);
    pairs[pos] = (s << BSHIFT) | (d & (BSZ - 1));
  }
}

// ---------------------------------------------------------------------------
// Fused per-bucket build: degree count -> 128-wide local exclusive scan ->
// off[] + dis[] -> CSR fill. Offsets are bucket-local: base = histoff[b*NBLK].
// ---------------------------------------------------------------------------
__global__ __launch_bounds__(256) void k_build_bucket(
    const int* __restrict__ pairs, const int* __restrict__ histoff,
    int* __restrict__ off, float* __restrict__ dis, int* __restrict__ csr,
    int E, int N, int NBLK, int P) {
  __shared__ int lc[BSZ];
  __shared__ int lscan[BSZ];
  __shared__ int lcur[BSZ];
  int tid = threadIdx.x;
  int b = blockIdx.x;
  if (tid < BSZ) lc[tid] = 0;
  __syncthreads();
  int s0 = histoff[b * NBLK];
  int s1 = histoff[(b + 1) * NBLK];
  for (int i = s0 + tid; i < s1; i += 256)
    atomicAdd(&lc[pairs[i] & (BSZ - 1)], 1);
  __syncthreads();
  if (tid < BSZ) lscan[tid] = lc[tid];
  __syncthreads();
#pragma unroll
  for (int o = 1; o < BSZ; o <<= 1) {
    int v = 0;
    if (tid < BSZ && tid >= o) v = lscan[tid - o];
    __syncthreads();
    if (tid < BSZ) lscan[tid] += v;
    __syncthreads();
  }
  int node = (b << BSHIFT) + tid;
  if (tid < BSZ) {
    int o_node = s0 + lscan[tid] - lc[tid];  // exclusive
    lcur[tid] = o_node;
    if (node < N) {
      off[node] = o_node;
      dis[node] = rsqrtf((float)(lc[tid] + 1));  // +1 self loop
    }
  }
  if (b == P - 1 && tid == 0) off[N] = E;
  __syncthreads();
  for (int i = s0 + tid; i < s1; i += 256) {
    int pk = pairs[i];
    int pos = atomicAdd(&lcur[pk & (BSZ - 1)], 1);
    csr[pos] = pk >> BSHIFT;
  }
}

// xs[row] = fp16(x[row] * dis[row])
__global__ __launch_bounds__(256) void k_scale(const float* __restrict__ x,
                                               const float* __restrict__ dis,
                                               __half* __restrict__ xs, int N) {
  int i = blockIdx.x * 256 + threadIdx.x;  // float4 index
  int total = N * 16;                      // 64 floats/row = 16 float4
  if (i < total) {
    float d = dis[i >> 4];
    float4 v = ((const float4*)x)[i];
    union { uint2 u; __half2 h[2]; } pk;
    pk.h[0] = __floats2half2_rn(v.x * d, v.y * d);
    pk.h[1] = __floats2half2_rn(v.z * d, v.w * d);
    ((uint2*)xs)[i] = pk.u;
  }
}

__device__ __forceinline__ float gelu_exact(float v) {
  return 0.5f * v * (1.0f + erff(v * 0.70710678118654752440f));
}

// ---------------------------------------------------------------------------
// R8 GEMM: 512 threads, 4x4 thread tile, full 32-wave occupancy.
// BM = 64 (M=128) or 128 (M=64). Per thread-k: 2 LDS float4 reads : 16 FMA.
// EPI=0: G = (X@W)*dis[row]; EPI=1: G = gelu((X@W)+bias).
// F16OUT=1: store fp16 (next gather table).
// ---------------------------------------------------------------------------
template <int K, int M, int EPI, int F16OUT>
__global__ __launch_bounds__(512, 8) void k_gemm4(
    const float* __restrict__ X, const float* __restrict__ W,
    const float* __restrict__ dis, const float* __restrict__ bias,
    void* __restrict__ Gout, int N) {
  constexpr int BM = (M == 128) ? 64 : 128;
  constexpr int BK = 16;
  constexpr int WQ = M / 4;   // float4 per W k-row (32 or 16)
  constexpr int TX = M / 4;   // column groups
  __shared__ float Wl[BK][M];
  __shared__ float Xl[BK][BM + 4];

  int tid = threadIdx.x;
  int tx = tid % TX;
  int ty = tid / TX;  // 0..15 (M=128) or 0..31 (M=64)
  int row0 = blockIdx.x * BM;

  float acc[4][4];
#pragma unroll
  for (int i = 0; i < 4; i++)
#pragma unroll
    for (int j = 0; j < 4; j++) acc[i][j] = 0.f;

  for (int kt = 0; kt < K; kt += BK) {
    // stage W tile (k-major direct): BK*WQ float4 tasks (512 or 256)
#pragma unroll
    for (int t = tid; t < BK * WQ; t += 512) {
      int krow = t / WQ, cq = t % WQ;
      *(float4*)&Wl[krow][cq * 4] =
          *(const float4*)&W[(size_t)(kt + krow) * M + cq * 4];
    }
    // stage X tile transposed: BM*(BK/4) tasks (256 or 512)
#pragma unroll
    for (int t = tid; t < BM * (BK / 4); t += 512) {
      int row = t >> 2, kq = t & 3;
      float4 v = make_float4(0.f, 0.f, 0.f, 0.f);
      if (row0 + row < N)
        v = *(const float4*)&X[(size_t)(row0 + row) * K + kt + kq * 4];
      Xl[kq * 4 + 0][row] = v.x;
      Xl[kq * 4 + 1][row] = v.y;
      Xl[kq * 4 + 2][row] = v.z;
      Xl[kq * 4 + 3][row] = v.w;
    }
    __syncthreads();
#pragma unroll
    for (int k = 0; k < BK; k++) {
      float xa[4], wa[4];
      *(float4*)&xa[0] = *(const float4*)&Xl[k][ty * 4];
      *(float4*)&wa[0] = *(const float4*)&Wl[k][tx * 4];
#pragma unroll
      for (int i = 0; i < 4; i++)
#pragma unroll
        for (int j = 0; j < 4; j++) acc[i][j] += xa[i] * wa[j];
    }
    __syncthreads();
  }

  float* Gf = (float*)Gout;
  __half* Gh = (__half*)Gout;
  int c0 = tx * 4;
#pragma unroll
  for (int i = 0; i < 4; i++) {
    int row = row0 + ty * 4 + i;
    if (row < N) {
      float4 o;
      if constexpr (EPI == 0) {
        float dd = dis[row];
        o.x = acc[i][0] * dd;
        o.y = acc[i][1] * dd;
        o.z = acc[i][2] * dd;
        o.w = acc[i][3] * dd;
      } else {
        o.x = gelu_exact(acc[i][0] + bias[c0 + 0]);
        o.y = gelu_exact(acc[i][1] + bias[c0 + 1]);
        o.z = gelu_exact(acc[i][2] + bias[c0 + 2]);
        o.w = gelu_exact(acc[i][3] + bias[c0 + 3]);
      }
      if constexpr (F16OUT) {
        union { uint2 u; __half2 h[2]; } pk;
        pk.h[0] = __floats2half2_rn(o.x, o.y);
        pk.h[1] = __floats2half2_rn(o.z, o.w);
        *(uint2*)&Gh[(size_t)row * M + c0] = pk.u;
      } else {
        *(float4*)&Gf[(size_t)row * M + c0] = o;
      }
    }
  }
}

__device__ __forceinline__ void acc8(float* a, uint4 r) {
  const __half2* h = reinterpret_cast<const __half2*>(&r);
#pragma unroll
  for (int q = 0; q < 4; q++) {
    float2 f = __half22float2(h[q]);
    a[2 * q] += f.x;
    a[2 * q + 1] += f.y;
  }
}

// ---------------------------------------------------------------------------
// fp16-table aggregation: 8 halves (16B) per lane, LPN = D/8 lanes per node,
// NPW = 64/LPN nodes per wave. fp32 accumulate, fp32 output. Unroll 8.
// ---------------------------------------------------------------------------
template <int D, bool HAS_BIAS, bool HAS_GELU>
__global__ __launch_bounds__(256) void k_agg(
    const __half* __restrict__ g, const int* __restrict__ off,
    const int* __restrict__ csr, const float* __restrict__ dis,
    const float* __restrict__ bias, float* __restrict__ out, int N) {
  constexpr int LPN = D / 8;     // lanes per node (16B of halves each)
  constexpr int NPW = 64 / LPN;  // nodes per wave
  int wave = (blockIdx.x * 256 + threadIdx.x) >> 6;
  int lane = threadIdx.x & 63;
  int sub = lane / LPN;
  int sl = lane % LPN;
  int node = wave * NPW + sub;
  if (node >= N) return;
  const uint4* G16 = (const uint4*)g;
  float a[8];
#pragma unroll
  for (int q = 0; q < 8; q++) a[q] = 0.f;
  acc8(a, G16[(size_t)node * LPN + sl]);  // self loop
  int beg = off[node], end = off[node + 1];
  int j = beg;
  for (; j + 8 <= end; j += 8) {
    uint4 r[8];
#pragma unroll
    for (int u = 0; u < 8; u++) r[u] = G16[(size_t)csr[j + u] * LPN + sl];
#pragma unroll
    for (int u = 0; u < 8; u++) acc8(a, r[u]);
  }
  for (; j + 4 <= end; j += 4) {
    uint4 r[4];
#pragma unroll
    for (int u = 0; u < 4; u++) r[u] = G16[(size_t)csr[j + u] * LPN + sl];
#pragma unroll
    for (int u = 0; u < 4; u++) acc8(a, r[u]);
  }
  for (; j < end; j++) acc8(a, G16[(size_t)csr[j] * LPN + sl]);
  float dd = dis[node];
  int c0 = sl * 8;
  float v[8];
#pragma unroll
  for (int q = 0; q < 8; q++) v[q] = a[q] * dd;
  if constexpr (HAS_BIAS) {
    float4 b0 = *(const float4*)&bias[c0];
    float4 b1 = *(const float4*)&bias[c0 + 4];
    v[0] += b0.x; v[1] += b0.y; v[2] += b0.z; v[3] += b0.w;
    v[4] += b1.x; v[5] += b1.y; v[6] += b1.z; v[7] += b1.w;
  }
  if constexpr (HAS_GELU) {
#pragma unroll
    for (int q = 0; q < 8; q++) v[q] = gelu_exact(v[q]);
  }
  float4 o0 = {v[0], v[1], v[2], v[3]};
  float4 o1 = {v[4], v[5], v[6], v[7]};
  *(float4*)&out[(size_t)node * D + c0] = o0;
  *(float4*)&out[(size_t)node * D + c0 + 4] = o1;
}

extern "C" void kernel_launch(void* const* d_in, const int* in_sizes, int n_in,
                              void* d_out, int out_size, void* d_ws,
                              size_t ws_size, hipStream_t stream) {
  const float* x = (const float*)d_in[0];
  const int* ei = (const int*)d_in[1];
  const float* W1 = (const float*)d_in[2];
  const float* b1 = (const float*)d_in[3];
  const float* W2 = (const float*)d_in[4];
  const float* b2 = (const float*)d_in[5];
  const float* W3 = (const float*)d_in[6];
  const float* b3 = (const float*)d_in[7];
  float* out = (float*)d_out;

  const int N = in_sizes[0] / 64;
  const int E = in_sizes[1] / 2;

  const int NBLK = (E + CHUNK - 1) / CHUNK;
  const int P = (N + BSZ - 1) >> BSHIFT;
  const int HT = P * NBLK;

  char* p = (char*)d_ws;
  auto alloc = [&](size_t bytes) {
    char* r = p;
    p += (bytes + 255) & ~(size_t)255;
    return r;
  };
  float* dis = (float*)alloc((size_t)N * 4);
  int* off = (int*)alloc((size_t)(N + 1) * 4);
  int* bsumH = (int*)alloc(4096);
  int* flag = (int*)alloc(256);
  int* hist = (int*)alloc((size_t)(HT + 1) * 4);
  int* histoff = (int*)alloc((size_t)(HT + 1) * 4);
  int* pairs = (int*)alloc((size_t)E * 4);
  int* csr = (int*)alloc((size_t)E * 4);
  float* bufA = (float*)alloc((size_t)N * 128 * 4);
  float* bufB = (float*)alloc((size_t)N * 128 * 4);
  __half* xsh = (__half*)alloc((size_t)N * 64 * 2);
  __half* gh = (__half*)alloc((size_t)N * 128 * 2);  // fp16 gather table

  const int NBH = (HT + 1023) / 1024;  // <= 1024 supported by k_scanB

  k_detect<<<1, 256, 0, stream>>>(ei, flag);
  k_hist<<<NBLK, 256, 0, stream>>>(ei, hist, E, N, NBLK, flag);
  k_scanA<<<NBH, 256, 0, stream>>>(hist, histoff, bsumH, HT);
  k_scanB<<<1, 256, 0, stream>>>(bsumH, NBH);
  k_scanC<<<(HT + 255) / 256, 256, 0, stream>>>(histoff, bsumH, HT, E);
  k_scatter<<<NBLK, 256, 0, stream>>>(ei, histoff, pairs, E, N, NBLK, flag);
  k_build_bucket<<<P, 256, 0, stream>>>(pairs, histoff, off, dis, csr, E, N,
                                        NBLK, P);

  const int gemm_blocks64 = (N + 63) / 64;    // BM=64 (M=128 kernels)
  const int gemm_blocks128 = (N + 127) / 128; // BM=128 (M=64 kernel)
  const int agg128_blocks = (N + 15) / 16;  // 4 nodes/wave, 4 waves/block
  const int agg64_blocks = (N + 31) / 32;   // 8 nodes/wave, 4 waves/block

  // layer 1 (swapped): xs = fp16(x*dis); Xa = agg(xs); h1 = gelu(Xa@W1 + b1)
  k_scale<<<(N * 16 + 255) / 256, 256, 0, stream>>>(x, dis, xsh, N);
  k_agg<64, false, false><<<agg64_blocks, 256, 0, stream>>>(xsh, off, csr, dis,
                                                            nullptr, bufB, N);
  k_gemm4<64, 128, 1, 0><<<gemm_blocks64, 512, 0, stream>>>(bufB, W1, nullptr,
                                                            b1, (void*)bufA, N);
  // layer 2: g = fp16((h1@W2)*dis); h2 = gelu(agg(g) + b2)
  k_gemm4<128, 128, 0, 1><<<gemm_blocks64, 512, 0, stream>>>(bufA, W2, dis,
                                                             nullptr, (void*)gh, N);
  k_agg<128, true, true><<<agg128_blocks, 256, 0, stream>>>(gh, off, csr, dis,
                                                            b2, bufB, N);
  // layer 3: g = fp16((h2@W3)*dis); out = agg(g) + b3
  k_gemm4<128, 64, 0, 1><<<gemm_blocks128, 512, 0, stream>>>(bufB, W3, dis,
                                                             nullptr, (void*)gh, N);
  k_agg<64, true, false><<<agg64_blocks, 256, 0, stream>>>(gh, off, csr, dis,
                                                           b3, out, N);
}

// Round 9
// 298.090 us; speedup vs baseline: 2.4506x; 1.0322x over previous
//
#include <hip/hip_runtime.h>
#include <hip/hip_fp16.h>
#include <cstdint>
#include <cstddef>

// ---------------------------------------------------------------------------
// GCN 3-layer forward on MI355X.
// Pipeline: detect idx dtype -> bucket-partition edges by dst -> fused
// per-bucket {degree, scan -> off/dis, CSR fill} -> layers.
// R3: layer 1 aggregates x at D=64 (A(XW)=(AX)W).
// R5: gather tables fp16 (agg FETCH floor = 8 XCDs x unique table lines;
//     measured 189MB vs 25.6MB table -> structural, L2-fill ~3.3TB/s).
// R6: fused build tail. R8: 512-thr GEMM, CHUNK 4096.
// R9: ALL intermediate node buffers fp16 (Xa, h1, h2) — agg F16OUT,
// gemm F16IN — cuts ~128MB streaming; agg unroll back to 4 (R8 showed
// unroll-8 neutral, only cost occupancy).
// ---------------------------------------------------------------------------

#define CHUNK 4096    // edges per partition block
#define BSHIFT 7      // bucket = dst >> 7  (128 nodes / bucket)
#define BSZ 128

__device__ __forceinline__ int eload(const int* ei, int elem, int is64) {
  return is64 ? ei[2 * elem] : ei[elem];
}

// Detect int64 vs int32 storage: for int64, high words of the first 1024
// elements are all zero (values in [0, N) < 2^31).
__global__ void k_detect(const int* __restrict__ ei, int* __restrict__ flag) {
  __shared__ int sh[256];
  int tid = threadIdx.x;
  int o = 0;
  for (int i = tid; i < 1024; i += 256) o |= ei[2 * i + 1];
  sh[tid] = o;
  __syncthreads();
  for (int s = 128; s > 0; s >>= 1) {
    if (tid < s) sh[tid] |= sh[tid + s];
    __syncthreads();
  }
  if (tid == 0) *flag = (sh[0] == 0) ? 1 : 0;
}

// per-chunk LDS histogram over dst buckets; hist is bucket-major [P][NBLK]
__global__ __launch_bounds__(256) void k_hist(const int* __restrict__ ei,
                                              int* __restrict__ hist, int E,
                                              int N, int NBLK,
                                              const int* __restrict__ flag) {
  __shared__ int lh[1024];
  int tid = threadIdx.x;
  int P = (N + BSZ - 1) >> BSHIFT;
  for (int i = tid; i < P; i += 256) lh[i] = 0;
  __syncthreads();
  int is64 = *flag;
  int e0 = blockIdx.x * CHUNK;
  int e1 = min(e0 + CHUNK, E);
  for (int e = e0 + tid; e < e1; e += 256) {
    int d = eload(ei, E + e, is64);
    atomicAdd(&lh[d >> BSHIFT], 1);
  }
  __syncthreads();
  for (int b = tid; b < P; b += 256) hist[b * NBLK + blockIdx.x] = lh[b];
}

// ---- generic 2-level exclusive scan (1024 elems / block) ----
__global__ __launch_bounds__(256) void k_scanA(const int* __restrict__ in,
                                               int* __restrict__ out,
                                               int* __restrict__ bsum, int n) {
  __shared__ int sh[256];
  int tid = threadIdx.x;
  int base = blockIdx.x * 1024 + tid * 4;
  int v0 = (base + 0 < n) ? in[base + 0] : 0;
  int v1 = (base + 1 < n) ? in[base + 1] : 0;
  int v2 = (base + 2 < n) ? in[base + 2] : 0;
  int v3 = (base + 3 < n) ? in[base + 3] : 0;
  int tsum = v0 + v1 + v2 + v3;
  sh[tid] = tsum;
  __syncthreads();
  for (int o = 1; o < 256; o <<= 1) {
    int x = (tid >= o) ? sh[tid - o] : 0;
    __syncthreads();
    sh[tid] += x;
    __syncthreads();
  }
  int excl = sh[tid] - tsum;
  if (base + 0 < n) out[base + 0] = excl;
  if (base + 1 < n) out[base + 1] = excl + v0;
  if (base + 2 < n) out[base + 2] = excl + v0 + v1;
  if (base + 3 < n) out[base + 3] = excl + v0 + v1 + v2;
  if (tid == 255) bsum[blockIdx.x] = sh[255];
}

// exclusive scan of up to 1024 block sums, in place (4 per thread)
__global__ __launch_bounds__(256) void k_scanB(int* __restrict__ bsum, int NB) {
  __shared__ int sh[256];
  int tid = threadIdx.x;
  int base = tid * 4;
  int v0 = (base + 0 < NB) ? bsum[base + 0] : 0;
  int v1 = (base + 1 < NB) ? bsum[base + 1] : 0;
  int v2 = (base + 2 < NB) ? bsum[base + 2] : 0;
  int v3 = (base + 3 < NB) ? bsum[base + 3] : 0;
  int tsum = v0 + v1 + v2 + v3;
  sh[tid] = tsum;
  __syncthreads();
  for (int o = 1; o < 256; o <<= 1) {
    int x = (tid >= o) ? sh[tid - o] : 0;
    __syncthreads();
    sh[tid] += x;
    __syncthreads();
  }
  int excl = sh[tid] - tsum;
  if (base + 0 < NB) bsum[base + 0] = excl;
  if (base + 1 < NB) bsum[base + 1] = excl + v0;
  if (base + 2 < NB) bsum[base + 2] = excl + v0 + v1;
  if (base + 3 < NB) bsum[base + 3] = excl + v0 + v1 + v2;
}

__global__ __launch_bounds__(256) void k_scanC(int* __restrict__ out,
                                               const int* __restrict__ bsum,
                                               int n, int total) {
  int i = blockIdx.x * 256 + threadIdx.x;
  if (i == 0) out[n] = total;
  if (i < n) out[i] += bsum[i >> 10];
}

// scatter edges into bucket-partitioned `pairs`, packed (src<<BSHIFT)|dst_lo.
__global__ __launch_bounds__(256) void k_scatter(const int* __restrict__ ei,
                                                 const int* __restrict__ histoff,
                                                 int* __restrict__ pairs, int E,
                                                 int N, int NBLK,
                                                 const int* __restrict__ flag) {
  __shared__ int lcur[1024];
  int tid = threadIdx.x;
  int P = (N + BSZ - 1) >> BSHIFT;
  for (int b = tid; b < P; b += 256)
    lcur[b] = histoff[b * NBLK + blockIdx.x];
  __syncthreads();
  int is64 = *flag;
  int e0 = blockIdx.x * CHUNK;
  int e1 = min(e0 + CHUNK, E);
  for (int e = e0 + tid; e < e1; e += 256) {
    int s = eload(ei, e, is64);
    int d = eload(ei, E + e, is64);
    int pos = atomicAdd(&lcur[d >> BSHIFT], 1);
    pairs[pos] = (s << BSHIFT) | (d & (BSZ - 1));
  }
}

// ---------------------------------------------------------------------------
// Fused per-bucket build: degree count -> 128-wide local exclusive scan ->
// off[] + dis[] -> CSR fill. Offsets are bucket-local: base = histoff[b*NBLK].
// ---------------------------------------------------------------------------
__global__ __launch_bounds__(256) void k_build_bucket(
    const int* __restrict__ pairs, const int* __restrict__ histoff,
    int* __restrict__ off, float* __restrict__ dis, int* __restrict__ csr,
    int E, int N, int NBLK, int P) {
  __shared__ int lc[BSZ];
  __shared__ int lscan[BSZ];
  __shared__ int lcur[BSZ];
  int tid = threadIdx.x;
  int b = blockIdx.x;
  if (tid < BSZ) lc[tid] = 0;
  __syncthreads();
  int s0 = histoff[b * NBLK];
  int s1 = histoff[(b + 1) * NBLK];
  for (int i = s0 + tid; i < s1; i += 256)
    atomicAdd(&lc[pairs[i] & (BSZ - 1)], 1);
  __syncthreads();
  if (tid < BSZ) lscan[tid] = lc[tid];
  __syncthreads();
#pragma unroll
  for (int o = 1; o < BSZ; o <<= 1) {
    int v = 0;
    if (tid < BSZ && tid >= o) v = lscan[tid - o];
    __syncthreads();
    if (tid < BSZ) lscan[tid] += v;
    __syncthreads();
  }
  int node = (b << BSHIFT) + tid;
  if (tid < BSZ) {
    int o_node = s0 + lscan[tid] - lc[tid];  // exclusive
    lcur[tid] = o_node;
    if (node < N) {
      off[node] = o_node;
      dis[node] = rsqrtf((float)(lc[tid] + 1));  // +1 self loop
    }
  }
  if (b == P - 1 && tid == 0) off[N] = E;
  __syncthreads();
  for (int i = s0 + tid; i < s1; i += 256) {
    int pk = pairs[i];
    int pos = atomicAdd(&lcur[pk & (BSZ - 1)], 1);
    csr[pos] = pk >> BSHIFT;
  }
}

// xs[row] = fp16(x[row] * dis[row])
__global__ __launch_bounds__(256) void k_scale(const float* __restrict__ x,
                                               const float* __restrict__ dis,
                                               __half* __restrict__ xs, int N) {
  int i = blockIdx.x * 256 + threadIdx.x;  // float4 index
  int total = N * 16;                      // 64 floats/row = 16 float4
  if (i < total) {
    float d = dis[i >> 4];
    float4 v = ((const float4*)x)[i];
    union { uint2 u; __half2 h[2]; } pk;
    pk.h[0] = __floats2half2_rn(v.x * d, v.y * d);
    pk.h[1] = __floats2half2_rn(v.z * d, v.w * d);
    ((uint2*)xs)[i] = pk.u;
  }
}

__device__ __forceinline__ float gelu_exact(float v) {
  return 0.5f * v * (1.0f + erff(v * 0.70710678118654752440f));
}

// ---------------------------------------------------------------------------
// R9 GEMM: 512 threads, 4x4 thread tile, full 32-wave occupancy.
// BM = 64 (M=128) or 128 (M=64). F16IN: X is fp16 (stage-convert to fp32 LDS).
// EPI=0: G = (X@W)*dis[row]; EPI=1: G = gelu((X@W)+bias).
// F16OUT=1: store fp16.
// ---------------------------------------------------------------------------
template <int K, int M, int EPI, int F16IN, int F16OUT>
__global__ __launch_bounds__(512, 8) void k_gemm4(
    const void* __restrict__ Xin, const float* __restrict__ W,
    const float* __restrict__ dis, const float* __restrict__ bias,
    void* __restrict__ Gout, int N) {
  constexpr int BM = (M == 128) ? 64 : 128;
  constexpr int BK = 16;
  constexpr int WQ = M / 4;   // float4 per W k-row
  constexpr int TX = M / 4;   // column groups
  __shared__ float Wl[BK][M];
  __shared__ float Xl[BK][BM + 4];

  int tid = threadIdx.x;
  int tx = tid % TX;
  int ty = tid / TX;
  int row0 = blockIdx.x * BM;

  float acc[4][4];
#pragma unroll
  for (int i = 0; i < 4; i++)
#pragma unroll
    for (int j = 0; j < 4; j++) acc[i][j] = 0.f;

  for (int kt = 0; kt < K; kt += BK) {
    // stage W tile (k-major direct)
#pragma unroll
    for (int t = tid; t < BK * WQ; t += 512) {
      int krow = t / WQ, cq = t % WQ;
      *(float4*)&Wl[krow][cq * 4] =
          *(const float4*)&W[(size_t)(kt + krow) * M + cq * 4];
    }
    // stage X tile transposed
#pragma unroll
    for (int t = tid; t < BM * (BK / 4); t += 512) {
      int row = t >> 2, kq = t & 3;
      float4 v = make_float4(0.f, 0.f, 0.f, 0.f);
      if (row0 + row < N) {
        if constexpr (F16IN) {
          const __half* Xh = (const __half*)Xin;
          uint2 raw = *(const uint2*)&Xh[(size_t)(row0 + row) * K + kt + kq * 4];
          const __half2* hh = reinterpret_cast<const __half2*>(&raw);
          float2 f0 = __half22float2(hh[0]);
          float2 f1 = __half22float2(hh[1]);
          v = make_float4(f0.x, f0.y, f1.x, f1.y);
        } else {
          const float* Xf = (const float*)Xin;
          v = *(const float4*)&Xf[(size_t)(row0 + row) * K + kt + kq * 4];
        }
      }
      Xl[kq * 4 + 0][row] = v.x;
      Xl[kq * 4 + 1][row] = v.y;
      Xl[kq * 4 + 2][row] = v.z;
      Xl[kq * 4 + 3][row] = v.w;
    }
    __syncthreads();
#pragma unroll
    for (int k = 0; k < BK; k++) {
      float xa[4], wa[4];
      *(float4*)&xa[0] = *(const float4*)&Xl[k][ty * 4];
      *(float4*)&wa[0] = *(const float4*)&Wl[k][tx * 4];
#pragma unroll
      for (int i = 0; i < 4; i++)
#pragma unroll
        for (int j = 0; j < 4; j++) acc[i][j] += xa[i] * wa[j];
    }
    __syncthreads();
  }

  float* Gf = (float*)Gout;
  __half* Gh = (__half*)Gout;
  int c0 = tx * 4;
#pragma unroll
  for (int i = 0; i < 4; i++) {
    int row = row0 + ty * 4 + i;
    if (row < N) {
      float4 o;
      if constexpr (EPI == 0) {
        float dd = dis[row];
        o.x = acc[i][0] * dd;
        o.y = acc[i][1] * dd;
        o.z = acc[i][2] * dd;
        o.w = acc[i][3] * dd;
      } else {
        o.x = gelu_exact(acc[i][0] + bias[c0 + 0]);
        o.y = gelu_exact(acc[i][1] + bias[c0 + 1]);
        o.z = gelu_exact(acc[i][2] + bias[c0 + 2]);
        o.w = gelu_exact(acc[i][3] + bias[c0 + 3]);
      }
      if constexpr (F16OUT) {
        union { uint2 u; __half2 h[2]; } pk;
        pk.h[0] = __floats2half2_rn(o.x, o.y);
        pk.h[1] = __floats2half2_rn(o.z, o.w);
        *(uint2*)&Gh[(size_t)row * M + c0] = pk.u;
      } else {
        *(float4*)&Gf[(size_t)row * M + c0] = o;
      }
    }
  }
}

__device__ __forceinline__ void acc8(float* a, uint4 r) {
  const __half2* h = reinterpret_cast<const __half2*>(&r);
#pragma unroll
  for (int q = 0; q < 4; q++) {
    float2 f = __half22float2(h[q]);
    a[2 * q] += f.x;
    a[2 * q + 1] += f.y;
  }
}

// ---------------------------------------------------------------------------
// fp16-table aggregation: 8 halves (16B) per lane, LPN = D/8 lanes per node,
// NPW = 64/LPN nodes per wave. fp32 accumulate. F16OUT: fp16 output buffer.
// ---------------------------------------------------------------------------
template <int D, bool HAS_BIAS, bool HAS_GELU, bool F16OUT>
__global__ __launch_bounds__(256) void k_agg(
    const __half* __restrict__ g, const int* __restrict__ off,
    const int* __restrict__ csr, const float* __restrict__ dis,
    const float* __restrict__ bias, void* __restrict__ outv, int N) {
  constexpr int LPN = D / 8;     // lanes per node (16B of halves each)
  constexpr int NPW = 64 / LPN;  // nodes per wave
  int wave = (blockIdx.x * 256 + threadIdx.x) >> 6;
  int lane = threadIdx.x & 63;
  int sub = lane / LPN;
  int sl = lane % LPN;
  int node = wave * NPW + sub;
  if (node >= N) return;
  const uint4* G16 = (const uint4*)g;
  float a[8];
#pragma unroll
  for (int q = 0; q < 8; q++) a[q] = 0.f;
  acc8(a, G16[(size_t)node * LPN + sl]);  // self loop
  int beg = off[node], end = off[node + 1];
  int j = beg;
  for (; j + 4 <= end; j += 4) {
    int s0 = csr[j], s1 = csr[j + 1], s2 = csr[j + 2], s3 = csr[j + 3];
    uint4 r0 = G16[(size_t)s0 * LPN + sl];
    uint4 r1 = G16[(size_t)s1 * LPN + sl];
    uint4 r2 = G16[(size_t)s2 * LPN + sl];
    uint4 r3 = G16[(size_t)s3 * LPN + sl];
    acc8(a, r0);
    acc8(a, r1);
    acc8(a, r2);
    acc8(a, r3);
  }
  for (; j < end; j++) acc8(a, G16[(size_t)csr[j] * LPN + sl]);
  float dd = dis[node];
  int c0 = sl * 8;
  float v[8];
#pragma unroll
  for (int q = 0; q < 8; q++) v[q] = a[q] * dd;
  if constexpr (HAS_BIAS) {
    float4 b0 = *(const float4*)&bias[c0];
    float4 b1 = *(const float4*)&bias[c0 + 4];
    v[0] += b0.x; v[1] += b0.y; v[2] += b0.z; v[3] += b0.w;
    v[4] += b1.x; v[5] += b1.y; v[6] += b1.z; v[7] += b1.w;
  }
  if constexpr (HAS_GELU) {
#pragma unroll
    for (int q = 0; q < 8; q++) v[q] = gelu_exact(v[q]);
  }
  if constexpr (F16OUT) {
    union { uint4 u; __half2 h[4]; } pk;
#pragma unroll
    for (int q = 0; q < 4; q++)
      pk.h[q] = __floats2half2_rn(v[2 * q], v[2 * q + 1]);
    *(uint4*)&((__half*)outv)[(size_t)node * D + c0] = pk.u;
  } else {
    float* out = (float*)outv;
    float4 o0 = {v[0], v[1], v[2], v[3]};
    float4 o1 = {v[4], v[5], v[6], v[7]};
    *(float4*)&out[(size_t)node * D + c0] = o0;
    *(float4*)&out[(size_t)node * D + c0 + 4] = o1;
  }
}

extern "C" void kernel_launch(void* const* d_in, const int* in_sizes, int n_in,
                              void* d_out, int out_size, void* d_ws,
                              size_t ws_size, hipStream_t stream) {
  const float* x = (const float*)d_in[0];
  const int* ei = (const int*)d_in[1];
  const float* W1 = (const float*)d_in[2];
  const float* b1 = (const float*)d_in[3];
  const float* W2 = (const float*)d_in[4];
  const float* b2 = (const float*)d_in[5];
  const float* W3 = (const float*)d_in[6];
  const float* b3 = (const float*)d_in[7];
  float* out = (float*)d_out;

  const int N = in_sizes[0] / 64;
  const int E = in_sizes[1] / 2;

  const int NBLK = (E + CHUNK - 1) / CHUNK;
  const int P = (N + BSZ - 1) >> BSHIFT;
  const int HT = P * NBLK;

  char* p = (char*)d_ws;
  auto alloc = [&](size_t bytes) {
    char* r = p;
    p += (bytes + 255) & ~(size_t)255;
    return r;
  };
  float* dis = (float*)alloc((size_t)N * 4);
  int* off = (int*)alloc((size_t)(N + 1) * 4);
  int* bsumH = (int*)alloc(4096);
  int* flag = (int*)alloc(256);
  int* hist = (int*)alloc((size_t)(HT + 1) * 4);
  int* histoff = (int*)alloc((size_t)(HT + 1) * 4);
  int* pairs = (int*)alloc((size_t)E * 4);
  int* csr = (int*)alloc((size_t)E * 4);
  __half* xsh = (__half*)alloc((size_t)N * 64 * 2);   // gather table L1
  __half* Xa_h = (__half*)alloc((size_t)N * 64 * 2);  // agg1 out / gemm1 in
  __half* h1_h = (__half*)alloc((size_t)N * 128 * 2); // gemm1 out / gemm2 in
  __half* gh = (__half*)alloc((size_t)N * 128 * 2);   // gemm2 out = table L2
  __half* h2_h = (__half*)alloc((size_t)N * 128 * 2); // agg2 out / gemm3 in
  __half* gh2 = (__half*)alloc((size_t)N * 64 * 2);   // gemm3 out = table L3

  const int NBH = (HT + 1023) / 1024;  // <= 1024 supported by k_scanB

  k_detect<<<1, 256, 0, stream>>>(ei, flag);
  k_hist<<<NBLK, 256, 0, stream>>>(ei, hist, E, N, NBLK, flag);
  k_scanA<<<NBH, 256, 0, stream>>>(hist, histoff, bsumH, HT);
  k_scanB<<<1, 256, 0, stream>>>(bsumH, NBH);
  k_scanC<<<(HT + 255) / 256, 256, 0, stream>>>(histoff, bsumH, HT, E);
  k_scatter<<<NBLK, 256, 0, stream>>>(ei, histoff, pairs, E, N, NBLK, flag);
  k_build_bucket<<<P, 256, 0, stream>>>(pairs, histoff, off, dis, csr, E, N,
                                        NBLK, P);

  const int gemm_blocks64 = (N + 63) / 64;    // BM=64 (M=128 kernels)
  const int gemm_blocks128 = (N + 127) / 128; // BM=128 (M=64 kernel)
  const int agg128_blocks = (N + 15) / 16;  // 4 nodes/wave, 4 waves/block
  const int agg64_blocks = (N + 31) / 32;   // 8 nodes/wave, 4 waves/block

  // layer 1 (swapped): xs = fp16(x*dis); Xa = agg(xs); h1 = gelu(Xa@W1 + b1)
  k_scale<<<(N * 16 + 255) / 256, 256, 0, stream>>>(x, dis, xsh, N);
  k_agg<64, false, false, true><<<agg64_blocks, 256, 0, stream>>>(
      xsh, off, csr, dis, nullptr, (void*)Xa_h, N);
  k_gemm4<64, 128, 1, 1, 1><<<gemm_blocks64, 512, 0, stream>>>(
      (const void*)Xa_h, W1, nullptr, b1, (void*)h1_h, N);
  // layer 2: g = fp16((h1@W2)*dis); h2 = fp16(gelu(agg(g) + b2))
  k_gemm4<128, 128, 0, 1, 1><<<gemm_blocks64, 512, 0, stream>>>(
      (const void*)h1_h, W2, dis, nullptr, (void*)gh, N);
  k_agg<128, true, true, true><<<agg128_blocks, 256, 0, stream>>>(
      gh, off, csr, dis, b2, (void*)h2_h, N);
  // layer 3: g = fp16((h2@W3)*dis); out = agg(g) + b3 (fp32)
  k_gemm4<128, 64, 0, 1, 1><<<gemm_blocks128, 512, 0, stream>>>(
      (const void*)h2_h, W3, dis, nullptr, (void*)gh2, N);
  k_agg<64, true, false, false><<<agg64_blocks, 256, 0, stream>>>(
      gh2, off, csr, dis, b3, (void*)out, N);
}

// Round 10
// 235.257 us; speedup vs baseline: 3.1051x; 1.2671x over previous
//
#include <hip/hip_runtime.h>
#include <hip/hip_fp16.h>
#include <cstdint>
#include <cstddef>

// ---------------------------------------------------------------------------
// GCN 3-layer forward on MI355X.
// Pipeline: detect idx dtype -> bucket-partition edges by dst -> fused
// per-bucket {degree, scan -> off/dis, CSR fill} -> layers.
// R3: layer 1 aggregates x at D=64 (A(XW)=(AX)W).
// R5/R9: all node-feature buffers fp16 (agg L2-fill floor = 8 XCDs x table).
// R6/R8: fused build tail; CHUNK 4096.
// R10: GEMMs moved to MFMA f16 (mfma_f32_16x16x32_f16, fp32 acc). Inputs
// were already fp16; W gets one extra fp16 rounding. Fragment-major W in
// LDS (lane slot = frag*1KB + lane*16B -> conflict-free ds_read_b128).
// fp32-VALU GEMM trio was ~95us at ~70TF; MFMA is streaming-bound ~35us.
// ---------------------------------------------------------------------------

#define CHUNK 4096    // edges per partition block
#define BSHIFT 7      // bucket = dst >> 7  (128 nodes / bucket)
#define BSZ 128

typedef _Float16 half8 __attribute__((ext_vector_type(8)));
typedef float floatx4 __attribute__((ext_vector_type(4)));

__device__ __forceinline__ int eload(const int* ei, int elem, int is64) {
  return is64 ? ei[2 * elem] : ei[elem];
}

// Detect int64 vs int32 storage: for int64, high words of the first 1024
// elements are all zero (values in [0, N) < 2^31).
__global__ void k_detect(const int* __restrict__ ei, int* __restrict__ flag) {
  __shared__ int sh[256];
  int tid = threadIdx.x;
  int o = 0;
  for (int i = tid; i < 1024; i += 256) o |= ei[2 * i + 1];
  sh[tid] = o;
  __syncthreads();
  for (int s = 128; s > 0; s >>= 1) {
    if (tid < s) sh[tid] |= sh[tid + s];
    __syncthreads();
  }
  if (tid == 0) *flag = (sh[0] == 0) ? 1 : 0;
}

// per-chunk LDS histogram over dst buckets; hist is bucket-major [P][NBLK]
__global__ __launch_bounds__(256) void k_hist(const int* __restrict__ ei,
                                              int* __restrict__ hist, int E,
                                              int N, int NBLK,
                                              const int* __restrict__ flag) {
  __shared__ int lh[1024];
  int tid = threadIdx.x;
  int P = (N + BSZ - 1) >> BSHIFT;
  for (int i = tid; i < P; i += 256) lh[i] = 0;
  __syncthreads();
  int is64 = *flag;
  int e0 = blockIdx.x * CHUNK;
  int e1 = min(e0 + CHUNK, E);
  for (int e = e0 + tid; e < e1; e += 256) {
    int d = eload(ei, E + e, is64);
    atomicAdd(&lh[d >> BSHIFT], 1);
  }
  __syncthreads();
  for (int b = tid; b < P; b += 256) hist[b * NBLK + blockIdx.x] = lh[b];
}

// ---- generic 2-level exclusive scan (1024 elems / block) ----
__global__ __launch_bounds__(256) void k_scanA(const int* __restrict__ in,
                                               int* __restrict__ out,
                                               int* __restrict__ bsum, int n) {
  __shared__ int sh[256];
  int tid = threadIdx.x;
  int base = blockIdx.x * 1024 + tid * 4;
  int v0 = (base + 0 < n) ? in[base + 0] : 0;
  int v1 = (base + 1 < n) ? in[base + 1] : 0;
  int v2 = (base + 2 < n) ? in[base + 2] : 0;
  int v3 = (base + 3 < n) ? in[base + 3] : 0;
  int tsum = v0 + v1 + v2 + v3;
  sh[tid] = tsum;
  __syncthreads();
  for (int o = 1; o < 256; o <<= 1) {
    int x = (tid >= o) ? sh[tid - o] : 0;
    __syncthreads();
    sh[tid] += x;
    __syncthreads();
  }
  int excl = sh[tid] - tsum;
  if (base + 0 < n) out[base + 0] = excl;
  if (base + 1 < n) out[base + 1] = excl + v0;
  if (base + 2 < n) out[base + 2] = excl + v0 + v1;
  if (base + 3 < n) out[base + 3] = excl + v0 + v1 + v2;
  if (tid == 255) bsum[blockIdx.x] = sh[255];
}

// exclusive scan of up to 1024 block sums, in place (4 per thread)
__global__ __launch_bounds__(256) void k_scanB(int* __restrict__ bsum, int NB) {
  __shared__ int sh[256];
  int tid = threadIdx.x;
  int base = tid * 4;
  int v0 = (base + 0 < NB) ? bsum[base + 0] : 0;
  int v1 = (base + 1 < NB) ? bsum[base + 1] : 0;
  int v2 = (base + 2 < NB) ? bsum[base + 2] : 0;
  int v3 = (base + 3 < NB) ? bsum[base + 3] : 0;
  int tsum = v0 + v1 + v2 + v3;
  sh[tid] = tsum;
  __syncthreads();
  for (int o = 1; o < 256; o <<= 1) {
    int x = (tid >= o) ? sh[tid - o] : 0;
    __syncthreads();
    sh[tid] += x;
    __syncthreads();
  }
  int excl = sh[tid] - tsum;
  if (base + 0 < NB) bsum[base + 0] = excl;
  if (base + 1 < NB) bsum[base + 1] = excl + v0;
  if (base + 2 < NB) bsum[base + 2] = excl + v0 + v1;
  if (base + 3 < NB) bsum[base + 3] = excl + v0 + v1 + v2;
}

__global__ __launch_bounds__(256) void k_scanC(int* __restrict__ out,
                                               const int* __restrict__ bsum,
                                               int n, int total) {
  int i = blockIdx.x * 256 + threadIdx.x;
  if (i == 0) out[n] = total;
  if (i < n) out[i] += bsum[i >> 10];
}

// scatter edges into bucket-partitioned `pairs`, packed (src<<BSHIFT)|dst_lo.
__global__ __launch_bounds__(256) void k_scatter(const int* __restrict__ ei,
                                                 const int* __restrict__ histoff,
                                                 int* __restrict__ pairs, int E,
                                                 int N, int NBLK,
                                                 const int* __restrict__ flag) {
  __shared__ int lcur[1024];
  int tid = threadIdx.x;
  int P = (N + BSZ - 1) >> BSHIFT;
  for (int b = tid; b < P; b += 256)
    lcur[b] = histoff[b * NBLK + blockIdx.x];
  __syncthreads();
  int is64 = *flag;
  int e0 = blockIdx.x * CHUNK;
  int e1 = min(e0 + CHUNK, E);
  for (int e = e0 + tid; e < e1; e += 256) {
    int s = eload(ei, e, is64);
    int d = eload(ei, E + e, is64);
    int pos = atomicAdd(&lcur[d >> BSHIFT], 1);
    pairs[pos] = (s << BSHIFT) | (d & (BSZ - 1));
  }
}

// ---------------------------------------------------------------------------
// Fused per-bucket build: degree count -> 128-wide local exclusive scan ->
// off[] + dis[] -> CSR fill. Offsets are bucket-local: base = histoff[b*NBLK].
// ---------------------------------------------------------------------------
__global__ __launch_bounds__(256) void k_build_bucket(
    const int* __restrict__ pairs, const int* __restrict__ histoff,
    int* __restrict__ off, float* __restrict__ dis, int* __restrict__ csr,
    int E, int N, int NBLK, int P) {
  __shared__ int lc[BSZ];
  __shared__ int lscan[BSZ];
  __shared__ int lcur[BSZ];
  int tid = threadIdx.x;
  int b = blockIdx.x;
  if (tid < BSZ) lc[tid] = 0;
  __syncthreads();
  int s0 = histoff[b * NBLK];
  int s1 = histoff[(b + 1) * NBLK];
  for (int i = s0 + tid; i < s1; i += 256)
    atomicAdd(&lc[pairs[i] & (BSZ - 1)], 1);
  __syncthreads();
  if (tid < BSZ) lscan[tid] = lc[tid];
  __syncthreads();
#pragma unroll
  for (int o = 1; o < BSZ; o <<= 1) {
    int v = 0;
    if (tid < BSZ && tid >= o) v = lscan[tid - o];
    __syncthreads();
    if (tid < BSZ) lscan[tid] += v;
    __syncthreads();
  }
  int node = (b << BSHIFT) + tid;
  if (tid < BSZ) {
    int o_node = s0 + lscan[tid] - lc[tid];  // exclusive
    lcur[tid] = o_node;
    if (node < N) {
      off[node] = o_node;
      dis[node] = rsqrtf((float)(lc[tid] + 1));  // +1 self loop
    }
  }
  if (b == P - 1 && tid == 0) off[N] = E;
  __syncthreads();
  for (int i = s0 + tid; i < s1; i += 256) {
    int pk = pairs[i];
    int pos = atomicAdd(&lcur[pk & (BSZ - 1)], 1);
    csr[pos] = pk >> BSHIFT;
  }
}

// xs[row] = fp16(x[row] * dis[row])
__global__ __launch_bounds__(256) void k_scale(const float* __restrict__ x,
                                               const float* __restrict__ dis,
                                               __half* __restrict__ xs, int N) {
  int i = blockIdx.x * 256 + threadIdx.x;  // float4 index
  int total = N * 16;                      // 64 floats/row = 16 float4
  if (i < total) {
    float d = dis[i >> 4];
    float4 v = ((const float4*)x)[i];
    union { uint2 u; __half2 h[2]; } pk;
    pk.h[0] = __floats2half2_rn(v.x * d, v.y * d);
    pk.h[1] = __floats2half2_rn(v.z * d, v.w * d);
    ((uint2*)xs)[i] = pk.u;
  }
}

__device__ __forceinline__ float gelu_exact(float v) {
  return 0.5f * v * (1.0f + erff(v * 0.70710678118654752440f));
}

// ---------------------------------------------------------------------------
// R10 MFMA GEMM (fp16 in, fp32 acc, fp16 out).
// Block: 256 thr = 4 waves x 16 rows = 64 rows. Grid (N+63)/64.
// W staged fp16 fragment-major in LDS: frag (nt,kk), lane l holds
// W[kk*32+(l>>4)*8 + e][nt*16+(l&15)] at WtL[(fid*64+l)*8] -> ds_read_b128
// conflict-free. A frags straight from global (16B/lane).
// MFMA layouts (m89/m97-verified): A row=l&15, k=8*(l>>4)+e;
// D col=l&15, row=4*(l>>4)+reg.
// EPI=0: out = (X@W)*dis[row]; EPI=1: out = gelu((X@W)+bias).
// ---------------------------------------------------------------------------
template <int K, int M, int EPI>
__global__ __launch_bounds__(256) void k_gemm5(
    const __half* __restrict__ X, const float* __restrict__ W,
    const float* __restrict__ dis, const float* __restrict__ bias,
    __half* __restrict__ G, int N) {
  constexpr int NT = M / 16;   // n-tiles
  constexpr int KK = K / 32;   // k-steps
  __shared__ _Float16 WtL[M * K];  // fragment-major

  int tid = threadIdx.x;
  // stage W as fp16 fragments: task t -> frag id (t>>6), lane slot (t&63)
  for (int t = tid; t < M * K / 8; t += 256) {
    int l = t & 63;
    int fid = t >> 6;
    int nt = fid / KK, kk = fid % KK;
    int n = nt * 16 + (l & 15);
    int k0 = kk * 32 + (l >> 4) * 8;
    half8 h;
#pragma unroll
    for (int e = 0; e < 8; e++)
      h[e] = (_Float16)W[(size_t)(k0 + e) * M + n];
    *(half8*)&WtL[(size_t)t * 8] = h;
  }
  __syncthreads();

  int wave = tid >> 6, l = tid & 63;
  int lr = l & 15, lg = l >> 4;
  int row0 = blockIdx.x * 64 + wave * 16;

  // load A fragments from global
  half8 a[KK];
  {
    int row = min(row0 + lr, N - 1);
    const __half* xp = X + (size_t)row * K + lg * 8;
#pragma unroll
    for (int kk = 0; kk < KK; kk++)
      a[kk] = *(const half8*)(xp + kk * 32);
  }

  floatx4 acc[NT];
#pragma unroll
  for (int nt = 0; nt < NT; nt++) acc[nt] = {0.f, 0.f, 0.f, 0.f};

#pragma unroll
  for (int nt = 0; nt < NT; nt++) {
#pragma unroll
    for (int kk = 0; kk < KK; kk++) {
      half8 b = *(const half8*)&WtL[(size_t)((nt * KK + kk) * 64 + l) * 8];
      acc[nt] = __builtin_amdgcn_mfma_f32_16x16x32_f16(a[kk], b, acc[nt], 0, 0, 0);
    }
  }

  // epilogue: lane l, reg r -> row = row0 + lg*4 + r, col = nt*16 + lr
#pragma unroll
  for (int r = 0; r < 4; r++) {
    int row = row0 + lg * 4 + r;
    if (row < N) {
      float dd = (EPI == 0) ? dis[row] : 0.f;
#pragma unroll
      for (int nt = 0; nt < NT; nt++) {
        int col = nt * 16 + lr;
        float v = acc[nt][r];
        if constexpr (EPI == 0) v *= dd;
        else v = gelu_exact(v + bias[col]);
        G[(size_t)row * M + col] = __float2half(v);
      }
    }
  }
}

__device__ __forceinline__ void acc8(float* a, uint4 r) {
  const __half2* h = reinterpret_cast<const __half2*>(&r);
#pragma unroll
  for (int q = 0; q < 4; q++) {
    float2 f = __half22float2(h[q]);
    a[2 * q] += f.x;
    a[2 * q + 1] += f.y;
  }
}

// ---------------------------------------------------------------------------
// fp16-table aggregation: 8 halves (16B) per lane, LPN = D/8 lanes per node,
// NPW = 64/LPN nodes per wave. fp32 accumulate. F16OUT: fp16 output buffer.
// ---------------------------------------------------------------------------
template <int D, bool HAS_BIAS, bool HAS_GELU, bool F16OUT>
__global__ __launch_bounds__(256) void k_agg(
    const __half* __restrict__ g, const int* __restrict__ off,
    const int* __restrict__ csr, const float* __restrict__ dis,
    const float* __restrict__ bias, void* __restrict__ outv, int N) {
  constexpr int LPN = D / 8;     // lanes per node (16B of halves each)
  constexpr int NPW = 64 / LPN;  // nodes per wave
  int wave = (blockIdx.x * 256 + threadIdx.x) >> 6;
  int lane = threadIdx.x & 63;
  int sub = lane / LPN;
  int sl = lane % LPN;
  int node = wave * NPW + sub;
  if (node >= N) return;
  const uint4* G16 = (const uint4*)g;
  float a[8];
#pragma unroll
  for (int q = 0; q < 8; q++) a[q] = 0.f;
  acc8(a, G16[(size_t)node * LPN + sl]);  // self loop
  int beg = off[node], end = off[node + 1];
  int j = beg;
  for (; j + 4 <= end; j += 4) {
    int s0 = csr[j], s1 = csr[j + 1], s2 = csr[j + 2], s3 = csr[j + 3];
    uint4 r0 = G16[(size_t)s0 * LPN + sl];
    uint4 r1 = G16[(size_t)s1 * LPN + sl];
    uint4 r2 = G16[(size_t)s2 * LPN + sl];
    uint4 r3 = G16[(size_t)s3 * LPN + sl];
    acc8(a, r0);
    acc8(a, r1);
    acc8(a, r2);
    acc8(a, r3);
  }
  for (; j < end; j++) acc8(a, G16[(size_t)csr[j] * LPN + sl]);
  float dd = dis[node];
  int c0 = sl * 8;
  float v[8];
#pragma unroll
  for (int q = 0; q < 8; q++) v[q] = a[q] * dd;
  if constexpr (HAS_BIAS) {
    float4 b0 = *(const float4*)&bias[c0];
    float4 b1 = *(const float4*)&bias[c0 + 4];
    v[0] += b0.x; v[1] += b0.y; v[2] += b0.z; v[3] += b0.w;
    v[4] += b1.x; v[5] += b1.y; v[6] += b1.z; v[7] += b1.w;
  }
  if constexpr (HAS_GELU) {
#pragma unroll
    for (int q = 0; q < 8; q++) v[q] = gelu_exact(v[q]);
  }
  if constexpr (F16OUT) {
    union { uint4 u; __half2 h[4]; } pk;
#pragma unroll
    for (int q = 0; q < 4; q++)
      pk.h[q] = __floats2half2_rn(v[2 * q], v[2 * q + 1]);
    *(uint4*)&((__half*)outv)[(size_t)node * D + c0] = pk.u;
  } else {
    float* out = (float*)outv;
    float4 o0 = {v[0], v[1], v[2], v[3]};
    float4 o1 = {v[4], v[5], v[6], v[7]};
    *(float4*)&out[(size_t)node * D + c0] = o0;
    *(float4*)&out[(size_t)node * D + c0 + 4] = o1;
  }
}

extern "C" void kernel_launch(void* const* d_in, const int* in_sizes, int n_in,
                              void* d_out, int out_size, void* d_ws,
                              size_t ws_size, hipStream_t stream) {
  const float* x = (const float*)d_in[0];
  const int* ei = (const int*)d_in[1];
  const float* W1 = (const float*)d_in[2];
  const float* b1 = (const float*)d_in[3];
  const float* W2 = (const float*)d_in[4];
  const float* b2 = (const float*)d_in[5];
  const float* W3 = (const float*)d_in[6];
  const float* b3 = (const float*)d_in[7];
  float* out = (float*)d_out;

  const int N = in_sizes[0] / 64;
  const int E = in_sizes[1] / 2;

  const int NBLK = (E + CHUNK - 1) / CHUNK;
  const int P = (N + BSZ - 1) >> BSHIFT;
  const int HT = P * NBLK;

  char* p = (char*)d_ws;
  auto alloc = [&](size_t bytes) {
    char* r = p;
    p += (bytes + 255) & ~(size_t)255;
    return r;
  };
  float* dis = (float*)alloc((size_t)N * 4);
  int* off = (int*)alloc((size_t)(N + 1) * 4);
  int* bsumH = (int*)alloc(4096);
  int* flag = (int*)alloc(256);
  int* hist = (int*)alloc((size_t)(HT + 1) * 4);
  int* histoff = (int*)alloc((size_t)(HT + 1) * 4);
  int* pairs = (int*)alloc((size_t)E * 4);
  int* csr = (int*)alloc((size_t)E * 4);
  __half* xsh = (__half*)alloc((size_t)N * 64 * 2);   // gather table L1
  __half* Xa_h = (__half*)alloc((size_t)N * 64 * 2);  // agg1 out / gemm1 in
  __half* h1_h = (__half*)alloc((size_t)N * 128 * 2); // gemm1 out / gemm2 in
  __half* gh = (__half*)alloc((size_t)N * 128 * 2);   // gemm2 out = table L2
  __half* h2_h = (__half*)alloc((size_t)N * 128 * 2); // agg2 out / gemm3 in
  __half* gh2 = (__half*)alloc((size_t)N * 64 * 2);   // gemm3 out = table L3

  const int NBH = (HT + 1023) / 1024;  // <= 1024 supported by k_scanB

  k_detect<<<1, 256, 0, stream>>>(ei, flag);
  k_hist<<<NBLK, 256, 0, stream>>>(ei, hist, E, N, NBLK, flag);
  k_scanA<<<NBH, 256, 0, stream>>>(hist, histoff, bsumH, HT);
  k_scanB<<<1, 256, 0, stream>>>(bsumH, NBH);
  k_scanC<<<(HT + 255) / 256, 256, 0, stream>>>(histoff, bsumH, HT, E);
  k_scatter<<<NBLK, 256, 0, stream>>>(ei, histoff, pairs, E, N, NBLK, flag);
  k_build_bucket<<<P, 256, 0, stream>>>(pairs, histoff, off, dis, csr, E, N,
                                        NBLK, P);

  const int gemm_blocks = (N + 63) / 64;    // 64 rows / block
  const int agg128_blocks = (N + 15) / 16;  // 4 nodes/wave, 4 waves/block
  const int agg64_blocks = (N + 31) / 32;   // 8 nodes/wave, 4 waves/block

  // layer 1 (swapped): xs = fp16(x*dis); Xa = agg(xs); h1 = gelu(Xa@W1 + b1)
  k_scale<<<(N * 16 + 255) / 256, 256, 0, stream>>>(x, dis, xsh, N);
  k_agg<64, false, false, true><<<agg64_blocks, 256, 0, stream>>>(
      xsh, off, csr, dis, nullptr, (void*)Xa_h, N);
  k_gemm5<64, 128, 1><<<gemm_blocks, 256, 0, stream>>>(Xa_h, W1, nullptr, b1,
                                                       h1_h, N);
  // layer 2: g = fp16((h1@W2)*dis); h2 = fp16(gelu(agg(g) + b2))
  k_gemm5<128, 128, 0><<<gemm_blocks, 256, 0, stream>>>(h1_h, W2, dis, nullptr,
                                                        gh, N);
  k_agg<128, true, true, true><<<agg128_blocks, 256, 0, stream>>>(
      gh, off, csr, dis, b2, (void*)h2_h, N);
  // layer 3: g = fp16((h2@W3)*dis); out = agg(g) + b3 (fp32)
  k_gemm5<128, 64, 0><<<gemm_blocks, 256, 0, stream>>>(h2_h, W3, dis, nullptr,
                                                       gh2, N);
  k_agg<64, true, false, false><<<agg64_blocks, 256, 0, stream>>>(
      gh2, off, csr, dis, b3, (void*)out, N);
}